// Round 18
// baseline (995.858 us; speedup 1.0000x reference)
//
#include <hip/hip_runtime.h>
#include <math.h>

#define N_PTS 16384
#define KNN 20
#define NRANGE 4
#define C_RANGE (N_PTS / NRANGE)       // 4096
// both knn kernels: 256-cand windows, ushort index queues
#define QCAPW 256                       // structural cap per query per window
#define QSW 257                         // ushort queue stride
#define HQS 65                          // hist stride (uints): (65*lq+b)%32 = (lq+b)%32

// histogram binning: b = (bits(u)>>22) - 222  -> half-octave bins (ratio sqrt(2)),
// covering [2^-16, 2^16) in 64 bins. upper_edge(b) = as_float((b+223)<<22).
#define HBIN_SHIFT 22
#define HBIN_BASE 222

// ---------------- bf16 helpers ----------------
__device__ __forceinline__ unsigned short f2bf(float f) {
  unsigned int u = __float_as_uint(f);
  unsigned int r = (u + 0x7fffu + ((u >> 16) & 1u)) >> 16;   // round-to-nearest-even
  return (unsigned short)r;
}
__device__ __forceinline__ float bf2f(unsigned short b) {
  return __uint_as_float(((unsigned int)b) << 16);
}

// ---------------- pack x: float4+norm AND packed bf16 rows (fused) ----------------
// A-row: [qh0,qh1,qh2, ql0,ql1,ql2]x2, 0 pad.  B-row: [ch]x2,[cl]x2, 0 pad.
// => sum_k A[k]B[k] = (qh+ql).(ch+cl) exactly (all cross terms represented).
// NOTE: the first 16 elements of each K=32 row form a complete, valid K=16 packing
// (12 used + 4 zeros) -- consumed by knn3's 32x32x16 MFMA with stride-32 reads.
__global__ void pack_kernel(const float* __restrict__ x, float4* __restrict__ xp,
                            unsigned short* __restrict__ xpa,
                            unsigned short* __restrict__ xpb) {
  int i = blockIdx.x*256 + threadIdx.x;   // 16384
  float v0 = x[i*3+0], v1 = x[i*3+1], v2 = x[i*3+2];
  {
    #pragma clang fp contract(off)
    xp[i] = make_float4(v0, v1, v2, v0*v0 + v1*v1 + v2*v2);
  }
  unsigned int h0 = f2bf(v0), h1 = f2bf(v1), h2 = f2bf(v2);
  unsigned int l0 = f2bf(v0 - bf2f((unsigned short)h0));
  unsigned int l1 = f2bf(v1 - bf2f((unsigned short)h1));
  unsigned int l2 = f2bf(v2 - bf2f((unsigned short)h2));
  unsigned int ua0 = h0 | (h1<<16), ua1 = h2 | (l0<<16), ua2 = l1 | (l2<<16);
  unsigned int ub0 = h0 | (h1<<16), ub1 = h2 | (h0<<16), ub2 = h1 | (h2<<16);
  unsigned int ub3 = l0 | (l1<<16), ub4 = l2 | (l0<<16), ub5 = l1 | (l2<<16);
  uint4* pa = (uint4*)(xpa + (size_t)i*32);
  uint4* pb = (uint4*)(xpb + (size_t)i*32);
  uint4 z; z.x = 0u; z.y = 0u; z.z = 0u; z.w = 0u;
  uint4 A0; A0.x = ua0; A0.y = ua1; A0.z = ua2; A0.w = ua0;
  uint4 A1; A1.x = ua1; A1.y = ua2; A1.z = 0u;  A1.w = 0u;
  uint4 B0; B0.x = ub0; B0.y = ub1; B0.z = ub2; B0.w = ub3;
  uint4 B1; B1.x = ub4; B1.y = ub5; B1.z = 0u;  B1.w = 0u;
  pa[0] = A0; pa[1] = A1; pa[2] = z; pa[3] = z;
  pb[0] = B0; pb[1] = B1; pb[2] = z; pb[3] = z;
}

__global__ void sq64_kernel(const float* __restrict__ h, float* __restrict__ sq) {
  int i = blockIdx.x * blockDim.x + threadIdx.x;
  const float4* r = (const float4*)(h + (long)i*64);
  {
    #pragma clang fp contract(off)
    float ax=0.f, ay=0.f, az=0.f, aw=0.f;
    for (int t=0; t<16; t++) {
      float4 v = r[t];
      ax += v.x*v.x; ay += v.y*v.y; az += v.z*v.z; aw += v.w*v.w;
    }
    sq[i] = (ax+ay)+(az+aw);
  }
}

// ---------------- seed64: graph-1 neighbor bound, 4 lanes/query (R15-proven) ----------------
__global__ __launch_bounds__(256, 2) void seed64_kernel(const float* __restrict__ h,
                                                        const float* __restrict__ sq,
                                                        const int* __restrict__ idx1,
                                                        float* __restrict__ wsd) {
  int gid = blockIdx.x*256 + threadIdx.x;   // 65536
  int i = gid >> 2, part = gid & 3;
  float4 q4[16];
  const float4* qrow = (const float4*)(h + (size_t)i*64);
  #pragma unroll
  for (int t=0;t<16;t++) q4[t] = qrow[t];
  float sqi = sq[i];
  float wmax = 0.f;
  for (int k=part*5;k<part*5+5;k++) {
    int j = idx1[i*KNN+k];
    const float4* crow = (const float4*)(h + (size_t)j*64);
    float acc = 0.f;
    #pragma unroll 4
    for (int t=0;t<16;t++) {
      float4 c = crow[t];
      acc += q4[t].x*c.x; acc += q4[t].y*c.y; acc += q4[t].z*c.z; acc += q4[t].w*c.w;
    }
    float sqj = sq[j];
    float d = (sqi + sqj) - 2.0f*acc;
    d += (sqi + sqj)*3e-5f + 1e-25f;
    wmax = fmaxf(wmax, d);
  }
  wmax = fmaxf(wmax, __shfl_xor(wmax, 1));
  wmax = fmaxf(wmax, __shfl_xor(wmax, 2));
  if (part == 0) wsd[i] = wmax;
}

// register top-20: replace current lex-max with (e,ei), rescan for new max.
__device__ __forceinline__ void t20_replace_rescan(float (&rd)[KNN], int (&ri)[KNN],
                                                   float &maxd, int &maxi, int &maxp,
                                                   float e, int ei) {
  #pragma unroll
  for (int k = 0; k < KNN; k++) if (k == maxp) { rd[k] = e; ri[k] = ei; }
  float md = rd[0]; int mi = ri[0]; int mp = 0;
  #pragma unroll
  for (int k = 1; k < KNN; k++) {
    bool g = (rd[k] > md) || (rd[k] == md && ri[k] > mi);
    md = g ? rd[k] : md; mi = g ? ri[k] : mi; mp = g ? k : mp;
  }
  maxd = md; maxi = mi; maxp = mp;
}

// wave-internal fence: drain outstanding LDS ops + stop compiler reordering.
// NOTE: lgkmcnt only — global loads issued before this stay in flight (prefetch survives).
#define WAVE_LDS_FENCE() asm volatile("s_waitcnt lgkmcnt(0)" ::: "memory")

typedef __bf16 bf16x8 __attribute__((ext_vector_type(8)));
typedef float f32x4 __attribute__((ext_vector_type(4)));
typedef float f32x16 __attribute__((ext_vector_type(16)));
#define MFMA16(A,B,C) __builtin_amdgcn_mfma_f32_16x16x32_bf16((A),(B),(C),0,0,0)
#define MFMA32(A,B,C) __builtin_amdgcn_mfma_f32_32x32x16_bf16((A),(B),(C),0,0,0)
#define SCALE3 0.9998f
#define SCALE_HH 0.995f   // hi-only deflation: RNE bf16 product err <= 2^-8, 2x term < 0.4%

// bin an inflated distance; returns [0,63]
__device__ __forceinline__ int hbin(float uu) {
  uu = fmaxf(uu, 1e-20f);
  int b = (int)(__float_as_uint(uu) >> HBIN_SHIFT) - HBIN_BASE;
  return b < 0 ? 0 : (b > 63 ? 63 : b);
}

// ---------------- knn D=64: wsd-seeded hi-only MFMA filter + exact fp32 confirm ----------------
// R8/R13/R15-proven config: 2 waves/block, 32 queries/wave, 256-cand windows (16 tiles in
// 4 rolling 4-tile chunks). Queue: ushort candidate index; drain rescores EVERY survivor
// with the bit-identical exact fp32 fmaf chain (drains near-empty under the wsd seed).
__global__ __launch_bounds__(128, 2) void knn64_wq(const float* __restrict__ h1,
                                                   const unsigned short* __restrict__ hbh,
                                                   const float* __restrict__ sqh,
                                                   const float* __restrict__ wsd,
                                                   float* __restrict__ pd,
                                                   int* __restrict__ pi) {
  __shared__ unsigned short qq[2][32][QSW];
  __shared__ float w19[2][32];
  __shared__ int   cnt[2][32];

  int tid = threadIdx.x;
  int wv = tid >> 6;
  int l  = tid & 63;
  int qb = blockIdx.x >> 2, rg = blockIdx.x & 3;
  int q0 = qb*64, c0 = rg*C_RANGE;
  int qw0 = q0 + wv*32;

  float rd[KNN]; int ri[KNN];
  #pragma unroll
  for (int k = 0; k < KNN; k++) { rd[k] = INFINITY; ri[k] = 0x7fffffff; }
  float maxd = INFINITY; int maxi = 0x7fffffff; int maxp = 0;

  float wsv = INFINITY, sqi = 0.f;
  if (l < 32) {
    wsv = wsd[qw0 + l]; sqi = sqh[qw0 + l];
    w19[wv][l] = wsv; cnt[wv][l] = 0;
  }

  int cn   = l & 15;           // fragment row selector
  int koff = (l >> 4) * 8;     // k-offset within 32-wide K block

  bf16x8 a00, a01, a10, a11;   // A fragments: 2 query groups, hi-only
  {
    size_t ar = (size_t)(qw0 + cn) * 64 + koff;
    a00 = *(const bf16x8*)(hbh + ar);
    a01 = *(const bf16x8*)(hbh + ar + 32);
    size_t br = (size_t)(qw0 + 16 + cn) * 64 + koff;
    a10 = *(const bf16x8*)(hbh + br);
    a11 = *(const bf16x8*)(hbh + br + 32);
  }

  float qsl[8], wq[8];
  #pragma unroll
  for (int v = 0; v < 8; v++)
    qsl[v] = sqh[qw0 + (v>>2)*16 + (l>>4)*4 + (v&3)] * SCALE_HH;
  WAVE_LDS_FENCE();
  #pragma unroll
  for (int v = 0; v < 8; v++) wq[v] = w19[wv][(v>>2)*16 + (l>>4)*4 + (v&3)];

  bf16x8 Bp[8], Bq[8]; float Cp[4], Cq[4];   // ping-pong 4-tile chunks

  #define LOADC64(WIN, T0, B, C) do { int cw_ = c0 + (WIN)*256;            \
    _Pragma("unroll")                                                      \
    for (int t_ = 0; t_ < 4; t_++) {                                       \
      size_t br_ = (size_t)(cw_ + ((T0)+t_)*16 + cn) * 64 + koff;          \
      B[2*t_]   = *(const bf16x8*)(hbh + br_);                             \
      B[2*t_+1] = *(const bf16x8*)(hbh + br_ + 32);                        \
      C[t_] = sqh[cw_ + ((T0)+t_)*16 + cn];                                \
    } } while (0)

  #define TILE64(T, B0, B1, CS) do {                                       \
    f32x4 z_ = {0.f, 0.f, 0.f, 0.f};                                       \
    f32x4 d0_ = MFMA16(a00, B0, z_); d0_ = MFMA16(a01, B1, d0_);           \
    f32x4 d1_ = MFMA16(a10, B0, z_); d1_ = MFMA16(a11, B1, d1_);           \
    float csl_ = (CS) * SCALE_HH;                                          \
    _Pragma("unroll")                                                      \
    for (int v = 0; v < 8; v++) {                                          \
      float av_ = (v < 4) ? d0_[v] : d1_[v-4];                             \
      float dd_ = fmaf(-2.f, av_, qsl[v] + csl_);                          \
      if (dd_ <= wq[v]) {                                                  \
        int lq_ = (v>>2)*16 + (l>>4)*4 + (v&3);                            \
        int slot_ = atomicAdd(&cnt[wv][lq_], 1);                           \
        qq[wv][lq_][slot_] = (unsigned short)((T)*16 + cn);                \
      }                                                                    \
    } } while (0)

  #define CHUNK64(B, C, T0)                                                \
    TILE64((T0)+0, B[0], B[1], C[0]); TILE64((T0)+1, B[2], B[3], C[1]);    \
    TILE64((T0)+2, B[4], B[5], C[2]); TILE64((T0)+3, B[6], B[7], C[3])

  LOADC64(0, 0, Bp, Cp);
  for (int win = 0; win < C_RANGE/256; win++) {    // 16 windows
    int cw0 = c0 + win*256;
    LOADC64(win, 4, Bq, Cq);
    CHUNK64(Bp, Cp, 0);
    LOADC64(win, 8, Bp, Cp);
    CHUNK64(Bq, Cq, 4);
    LOADC64(win, 12, Bq, Cq);
    CHUNK64(Bp, Cp, 8);
    if (win < C_RANGE/256 - 1) LOADC64(win+1, 0, Bp, Cp);  // pre-fence prefetch
    CHUNK64(Bq, Cq, 12);

    WAVE_LDS_FENCE();
    int myc = (l < 32) ? cnt[wv][l] : 0;
    if (__any(myc != 0)) {
      if (myc) {
        const float4* qr = (const float4*)(h1 + (size_t)(qw0 + l)*64);
        for (int s = 0; s < myc; s++) {
          int j = cw0 + (int)qq[wv][l][s];
          const float4* cr = (const float4*)(h1 + (size_t)j*64);
          float a = 0.f;
          #pragma unroll 4
          for (int t = 0; t < 16; t++) {
            float4 q = qr[t], c = cr[t];
            a = fmaf(q.x, c.x, a); a = fmaf(q.y, c.y, a);
            a = fmaf(q.z, c.z, a); a = fmaf(q.w, c.w, a);
          }
          float e = (sqi + sqh[j]) - 2.0f*a;
          if (e < maxd || (e == maxd && j < maxi))
            t20_replace_rescan(rd, ri, maxd, maxi, maxp, e, j);
        }
        cnt[wv][l] = 0;
        w19[wv][l] = fminf(maxd, wsv);
      }
      WAVE_LDS_FENCE();
      #pragma unroll
      for (int v = 0; v < 8; v++) wq[v] = w19[wv][(v>>2)*16 + (l>>4)*4 + (v&3)];
    }
  }
  #undef LOADC64
  #undef TILE64
  #undef CHUNK64

  if (l < 32) {
    size_t o = ((size_t)(qw0 + l)*NRANGE + rg)*KNN;
    for (int k = 0; k < KNN; k++) {
      float md = rd[0]; int mi = ri[0]; int mp = 0;
      #pragma unroll
      for (int t = 1; t < KNN; t++) {
        bool g = (rd[t] < md) || (rd[t] == md && ri[t] < mi);
        md = g ? rd[t] : md; mi = g ? ri[t] : mi; mp = g ? t : mp;
      }
      pd[o+k] = md; pi[o+k] = mi;
      #pragma unroll
      for (int t = 0; t < KNN; t++) if (t == mp) rd[t] = INFINITY;
    }
  }
}

// ---------------- knn D=3: 32x32x16 MFMA filter + subsampled-hist seed ----------------
// One MFMA-32 computes 32q x 32c (vs 4 MFMA-16): per 256-cand window MFMA issues 32->8,
// B/norm loads 16->8; push checks unchanged. Fragments read the FIRST 16 elements of the
// K=32 packed rows (a complete K=16 packing; stride 32 shorts). C/D map (m74/m101):
// col=lane&31, row=(reg&3)+8*(reg>>2)+4*(lane>>5). A/B: row=lane&31, koff=(lane>>5)*8.
// Acc rounding << 2e-4 deflation => push set still a superset; drains rescore exactly.
__global__ __launch_bounds__(128, 2) void knn3_wq(const float4* __restrict__ xp,
                                                  const unsigned short* __restrict__ xpa,
                                                  const unsigned short* __restrict__ xpb,
                                                  float* __restrict__ pd,
                                                  int* __restrict__ pi) {
  __shared__ unsigned short qq[2][32][QSW];
  __shared__ float w19[2][32];
  __shared__ int   cnt[2][32];

  int tid = threadIdx.x;
  int wv = tid >> 6;
  int l  = tid & 63;
  int qb = blockIdx.x >> 2, rg = blockIdx.x & 3;
  int q0 = qb*64, c0 = rg*C_RANGE;
  int qw0 = q0 + wv*32;

  float rd[KNN]; int ri[KNN];
  #pragma unroll
  for (int k = 0; k < KNN; k++) { rd[k] = INFINITY; ri[k] = 0x7fffffff; }
  float maxd = INFINITY; int maxi = 0x7fffffff; int maxp = 0;

  float4 qv4 = make_float4(0.f, 0.f, 0.f, 0.f);
  if (l < 32) {
    cnt[wv][l] = 0;
    qv4 = xp[qw0 + l];
  }

  int cn32  = l & 31;          // A/B row selector and D column
  int koff2 = (l >> 5) * 8;    // k-offset within K=16
  int hi    = l >> 5;

  bf16x8 aq = *(const bf16x8*)(xpa + (size_t)(qw0 + cn32)*32 + koff2);

  float qsr[16], qsp[16];
  #pragma unroll
  for (int v = 0; v < 16; v++) {
    int r = (v&3) + 8*(v>>2) + 4*hi;
    qsr[v] = xp[qw0 + r].w;
    qsp[v] = qsr[v] * SCALE3;
  }

  // ---- phase 1: subsampled histogram prologue (windows 0 and 8 = 512 cands) ----
  unsigned int* hw = (unsigned int*)&qq[wv][0][0];   // [32][HQS] uints, per wave
  for (int t = l; t < 32*HQS; t += 64) hw[t] = 0u;
  WAVE_LDS_FENCE();

  for (int win = 0; win < 16; win += 8) {
    int cw0 = c0 + win*256;
    #pragma unroll
    for (int t = 0; t < 8; t++) {
      int ct = cw0 + t*32;
      bf16x8 bb = *(const bf16x8*)(xpb + (size_t)(ct + cn32)*32 + koff2);
      f32x16 z = {0.f,0.f,0.f,0.f,0.f,0.f,0.f,0.f,0.f,0.f,0.f,0.f,0.f,0.f,0.f,0.f};
      f32x16 d = MFMA32(aq, bb, z);
      float csr = xp[ct + cn32].w;
      #pragma unroll
      for (int v = 0; v < 16; v++) {
        float uu = fmaf(-2.f, d[v], (qsr[v] + csr) * 1.0002f);  // >= exact distance
        int lq = (v&3) + 8*(v>>2) + 4*hi;
        atomicAdd(&hw[lq*HQS + hbin(uu)], 1u);
      }
    }
  }
  WAVE_LDS_FENCE();

  float wsv = INFINITY;
  if (l < 32) {
    unsigned int c = 0; int bsel = 64;
    for (int b = 0; b < 64; b++) {
      c += hw[l*HQS + b];
      if (bsel == 64 && c >= 20u) bsel = b;
    }
    if (bsel < 63)
      wsv = __uint_as_float((unsigned int)(bsel + HBIN_BASE + 1) << HBIN_SHIFT);
  }
  WAVE_LDS_FENCE();          // all lanes done reading hw before queue reuse
  if (l < 32) {
    w19[wv][l] = wsv;
    cnt[wv][l] = 0;
  }
  WAVE_LDS_FENCE();
  float wq[16];
  #pragma unroll
  for (int v = 0; v < 16; v++) wq[v] = w19[wv][(v&3) + 8*(v>>2) + 4*hi];

  // ---- phase 2: pipelined main scan (256-cand windows = 8 tiles of 32 cands) ----
  bf16x8 Bp[4], Bq[4]; float Cp[4], Cq[4];

  #define LOADC3(WIN, T0, B, C) do { int cw_ = c0 + (WIN)*256;             \
    _Pragma("unroll")                                                      \
    for (int t_ = 0; t_ < 4; t_++) {                                       \
      int ct_ = cw_ + ((T0)+t_)*32;                                        \
      B[t_] = *(const bf16x8*)(xpb + (size_t)(ct_ + cn32)*32 + koff2);     \
      C[t_] = xp[ct_ + cn32].w;                                            \
    } } while (0)

  #define TILE3(T, BB, CS) do {                                            \
    f32x16 z_ = {0.f,0.f,0.f,0.f,0.f,0.f,0.f,0.f,                          \
                 0.f,0.f,0.f,0.f,0.f,0.f,0.f,0.f};                         \
    f32x16 d_ = MFMA32(aq, BB, z_);                                        \
    float csp_ = (CS) * SCALE3;                                            \
    _Pragma("unroll")                                                      \
    for (int v = 0; v < 16; v++) {                                         \
      float dd_ = fmaf(-2.f, d_[v], qsp[v] + csp_);                        \
      if (dd_ <= wq[v]) {                                                  \
        int lq_ = (v&3) + 8*(v>>2) + 4*hi;                                 \
        int slot_ = atomicAdd(&cnt[wv][lq_], 1);                           \
        qq[wv][lq_][slot_] = (unsigned short)((T)*32 + cn32);              \
      }                                                                    \
    } } while (0)

  LOADC3(0, 0, Bp, Cp);
  for (int win = 0; win < 16; win++) {
    int cw0 = c0 + win*256;
    LOADC3(win, 4, Bq, Cq);
    TILE3(0, Bp[0], Cp[0]); TILE3(1, Bp[1], Cp[1]);
    TILE3(2, Bp[2], Cp[2]); TILE3(3, Bp[3], Cp[3]);
    if (win < 15) LOADC3(win+1, 0, Bp, Cp);   // pre-fence prefetch
    TILE3(4, Bq[0], Cq[0]); TILE3(5, Bq[1], Cq[1]);
    TILE3(6, Bq[2], Cq[2]); TILE3(7, Bq[3], Cq[3]);

    WAVE_LDS_FENCE();
    int myc = (l < 32) ? cnt[wv][l] : 0;
    if (__any(myc != 0)) {
      if (myc) {
        for (int s = 0; s < myc; s++) {
          int j = cw0 + (int)qq[wv][l][s];
          float4 cv4 = xp[j];
          float e = (qv4.w + cv4.w)
                  - 2.0f*(qv4.x*cv4.x + qv4.y*cv4.y + qv4.z*cv4.z);
          if (e < maxd || (e == maxd && j < maxi))
            t20_replace_rescan(rd, ri, maxd, maxi, maxp, e, j);
        }
        cnt[wv][l] = 0;
        w19[wv][l] = fminf(maxd, wsv);
      }
      WAVE_LDS_FENCE();
      #pragma unroll
      for (int v = 0; v < 16; v++) wq[v] = w19[wv][(v&3) + 8*(v>>2) + 4*hi];
    }
  }
  #undef LOADC3
  #undef TILE3

  if (l < 32) {
    size_t o = ((size_t)(qw0 + l)*NRANGE + rg)*KNN;
    for (int k = 0; k < KNN; k++) {
      float md = rd[0]; int mi = ri[0]; int mp = 0;
      #pragma unroll
      for (int t = 1; t < KNN; t++) {
        bool g = (rd[t] < md) || (rd[t] == md && ri[t] < mi);
        md = g ? rd[t] : md; mi = g ? ri[t] : mi; mp = g ? t : mp;
      }
      pd[o+k] = md; pi[o+k] = mi;
      #pragma unroll
      for (int t = 0; t < KNN; t++) if (t == mp) rd[t] = INFINITY;
    }
  }
}

// ---------------- merge NRANGE sorted partial lists -> top-20 ----------------
__global__ void knn_merge_kernel(const float* __restrict__ pd, const int* __restrict__ pi,
                                 int* __restrict__ out_idx) {
  int qi = blockIdx.x*256 + threadIdx.x;
  const float* bd = pd + (size_t)qi*NRANGE*KNN;
  const int*   bi = pi + (size_t)qi*NRANGE*KNN;
  int ptr[NRANGE];
  #pragma unroll
  for (int r=0;r<NRANGE;r++) ptr[r] = 0;
  for (int k = 0; k < KNN; k++) {
    float best = INFINITY; int besti = 0x7fffffff; int br = 0;
    #pragma unroll
    for (int r = 0; r < NRANGE; r++) {
      float d = bd[r*KNN + ptr[r]];
      int   ii = bi[r*KNN + ptr[r]];
      bool better = (ptr[r] < KNN) && (d < best || (d == best && ii < besti));
      if (better) { best = d; besti = ii; br = r; }
    }
    #pragma unroll
    for (int r=0;r<NRANGE;r++) ptr[r] += (r == br) ? 1 : 0;
    out_idx[qi*KNN + k] = besti;
  }
}

// ---------------- edge_conv1 precompute ----------------
__global__ void cg1_kernel(const float* __restrict__ x, const float* __restrict__ W1,
                           const float* __restrict__ b1,
                           float* __restrict__ C1, float* __restrict__ G1) {
  int gid = blockIdx.x*256 + threadIdx.x;   // 16384*64
  int i = gid >> 6, c = gid & 63;
  float x0 = x[i*3+0], x1 = x[i*3+1], x2 = x[i*3+2];
  float wt0 = W1[0*64+c], wt1 = W1[1*64+c], wt2 = W1[2*64+c];
  float wb0 = W1[3*64+c], wb1 = W1[4*64+c], wb2 = W1[5*64+c];
  C1[gid] = x0*(wt0-wb0) + x1*(wt1-wb1) + x2*(wt2-wb2) + b1[c];
  G1[gid] = x0*wb0 + x1*wb1 + x2*wb2;
}

// ---------------- gather+max+relu C=64, fused bf16-hi emit (h1 value is in registers) ----
__global__ void mrt64_kernel(const float* __restrict__ Ci, const float* __restrict__ G,
                             const int* __restrict__ idx, float* __restrict__ out,
                             unsigned short* __restrict__ bh) {
  int gid = blockIdx.x*256 + threadIdx.x;   // 16384*16
  int i = gid >> 4, c4 = gid & 15;
  float4 base = *(const float4*)(Ci + (size_t)i*64 + c4*4);
  float4 m = make_float4(-INFINITY, -INFINITY, -INFINITY, -INFINITY);
  for (int j=0; j<KNN; j++) {
    int jj = idx[i*KNN + j];
    float4 g = *(const float4*)(G + (size_t)jj*64 + c4*4);
    m.x = fmaxf(m.x, base.x + g.x); m.y = fmaxf(m.y, base.y + g.y);
    m.z = fmaxf(m.z, base.z + g.z); m.w = fmaxf(m.w, base.w + g.w);
  }
  float4 o;
  o.x = fmaxf(m.x, 0.0f); o.y = fmaxf(m.y, 0.0f);
  o.z = fmaxf(m.z, 0.0f); o.w = fmaxf(m.w, 0.0f);
  *(float4*)(out + (size_t)i*64 + c4*4) = o;
  ushort4 hv;
  hv.x = f2bf(o.x); hv.y = f2bf(o.y); hv.z = f2bf(o.z); hv.w = f2bf(o.w);
  ((ushort4*)bh)[i*16 + c4] = hv;
}

// ---------------- edge_conv2 precompute (wd2 fused inline, bit-identical) ----------------
__global__ void cg2_kernel(const float* __restrict__ h1, const float* __restrict__ W2,
                           const float* __restrict__ b2,
                           float* __restrict__ C2, float* __restrict__ G2) {
  int gid = blockIdx.x*256 + threadIdx.x;   // 16384*128
  int i = gid >> 7, c = gid & 127;
  float a = 0.f, g = 0.f;
  for (int d=0; d<64; d++) {
    float hv = h1[i*64 + d];
    float wt = W2[d*128 + c];
    float wb = W2[(d+64)*128 + c];
    a += hv * (wt - wb);
    g += hv * wb;
  }
  C2[gid] = a + b2[c];
  G2[gid] = g;
}

// ---------------- fused maxrelu(C=128) + fc1(relu) + fc2: one block per point ----------------
__global__ __launch_bounds__(128) void mrfc_kernel(const float* __restrict__ C2,
                                                   const float* __restrict__ G2,
                                                   const int* __restrict__ idx,
                                                   const float* __restrict__ w1,
                                                   const float* __restrict__ b1,
                                                   const float* __restrict__ w2,
                                                   const float* __restrict__ b2,
                                                   float* __restrict__ out) {
  __shared__ float h2r[128];
  __shared__ float f1r[128];
  int i = blockIdx.x, c = threadIdx.x;
  float base = C2[(size_t)i*128 + c];
  float m = -INFINITY;
  for (int j = 0; j < KNN; j++) {
    int jj = idx[i*KNN + j];
    m = fmaxf(m, base + G2[(size_t)jj*128 + c]);
  }
  h2r[c] = fmaxf(m, 0.0f);
  __syncthreads();
  float a = 0.f;
  for (int d = 0; d < 128; d++) a += h2r[d] * w1[d*128 + c];
  f1r[c] = fmaxf(a + b1[c], 0.0f);
  __syncthreads();
  if (c < 40) {
    float a2 = 0.f;
    for (int d = 0; d < 128; d++) a2 += f1r[d] * w2[d*40 + c];
    out[i*40 + c] = a2 + b2[c];
  }
}

extern "C" void kernel_launch(void* const* d_in, const int* in_sizes, int n_in,
                              void* d_out, int out_size, void* d_ws, size_t ws_size,
                              hipStream_t stream) {
  (void)in_sizes; (void)n_in; (void)out_size; (void)ws_size;
  const float* x     = (const float*)d_in[0];
  const float* W1    = (const float*)d_in[1];
  const float* b1    = (const float*)d_in[2];
  const float* W2    = (const float*)d_in[3];
  const float* b2    = (const float*)d_in[4];
  const float* fc1_w = (const float*)d_in[5];
  const float* fc1_b = (const float*)d_in[6];
  const float* fc2_w = (const float*)d_in[7];
  const float* fc2_b = (const float*)d_in[8];
  float* out = (float*)d_out;

  // ---- workspace (31.03 MB, lifetime-disjoint aliasing; R15 layout) ----
  char* ws = (char*)d_ws;
  float4* xp4 = (float4*)(ws + 0);          // 262144
  float*  sqh = (float*) (ws + 262144);     // 65536
  int*    idx = (int*)   (ws + 327680);     // 1310720
  float*  h1  = (float*) (ws + 1671168);    // 4194304 -> 5865472
  unsigned short* xpa = (unsigned short*)(ws + 1671168); // 1MB, dead before h1 written
  unsigned short* xpb = (unsigned short*)(ws + 2719744); // 1MB, dead before h1 written
  unsigned short* hbh = (unsigned short*)(ws + 5865472); // 2097152 -> 7962624
  float*  wsd = (float*) (ws + 10059776);   // 65536
  float*  A   = (float*) (ws + 14254080);   // 8388608 -> 22642688
  float*  C1  = A;
  float*  G1  = (float*) (ws + 14254080 + 4194304);
  float*  C2  = A;
  float*  G2  = (float*) (ws + 22642688);   // 8388608 -> 31031296
  int*    pi  = (int*)   (ws + 14254080);   // 5.25MB (aliases A; A dead during knn phases)
  float*  pd  = (float*) (ws + 22642688);   // 5.25MB (aliases G2; G2 dead during knn phases)

  pack_kernel  <<<64,    256, 0, stream>>>(x, xp4, xpa, xpb);
  knn3_wq      <<<1024,  128, 0, stream>>>(xp4, xpa, xpb, pd, pi);
  knn_merge_kernel<<<64, 256, 0, stream>>>(pd, pi, idx);
  cg1_kernel   <<<4096,  256, 0, stream>>>(x, W1, b1, C1, G1);
  mrt64_kernel <<<1024,  256, 0, stream>>>(C1, G1, idx, h1, hbh);
  sq64_kernel  <<<64,    256, 0, stream>>>(h1, sqh);
  seed64_kernel<<<256,   256, 0, stream>>>(h1, sqh, idx, wsd);
  knn64_wq     <<<1024,  128, 0, stream>>>(h1, hbh, sqh, wsd, pd, pi);
  knn_merge_kernel<<<64, 256, 0, stream>>>(pd, pi, idx);
  cg2_kernel   <<<8192,  256, 0, stream>>>(h1, W2, b2, C2, G2);
  mrfc_kernel  <<<16384, 128, 0, stream>>>(C2, G2, idx, fc1_w, fc1_b, fc2_w, fc2_b, out);
}

// Round 19
// 945.246 us; speedup vs baseline: 1.0535x; 1.0535x over previous
//
#include <hip/hip_runtime.h>
#include <math.h>

#define N_PTS 16384
#define KNN 20
#define NRANGE 4
#define C_RANGE (N_PTS / NRANGE)       // 4096
// both knn kernels: 256-cand windows (16 tiles), ushort index queues
#define QCAPW 256                       // structural: 16 lanes x 16 tiles
#define QSW 257                         // ushort queue stride
#define HQS 65                          // hist stride (uints): (65*lq+b)%32 = (lq+b)%32

// histogram binning: b = (bits(u)>>22) - 222  -> half-octave bins (ratio sqrt(2)),
// covering [2^-16, 2^16) in 64 bins. upper_edge(b) = as_float((b+223)<<22).
#define HBIN_SHIFT 22
#define HBIN_BASE 222

// ---------------- bf16 helpers ----------------
__device__ __forceinline__ unsigned short f2bf(float f) {
  unsigned int u = __float_as_uint(f);
  unsigned int r = (u + 0x7fffu + ((u >> 16) & 1u)) >> 16;   // round-to-nearest-even
  return (unsigned short)r;
}
__device__ __forceinline__ float bf2f(unsigned short b) {
  return __uint_as_float(((unsigned int)b) << 16);
}

// ---------------- pack x: float4+norm AND packed K=32 bf16 rows (fused) ----------------
// A-row: [qh0,qh1,qh2, ql0,ql1,ql2]x2, 0 pad.  B-row: [ch]x2,[cl]x2, 0 pad.
// => sum_k A[k]B[k] = (qh+ql).(ch+cl) exactly (all cross terms represented).
__global__ void pack_kernel(const float* __restrict__ x, float4* __restrict__ xp,
                            unsigned short* __restrict__ xpa,
                            unsigned short* __restrict__ xpb) {
  int i = blockIdx.x*256 + threadIdx.x;   // 16384
  float v0 = x[i*3+0], v1 = x[i*3+1], v2 = x[i*3+2];
  {
    #pragma clang fp contract(off)
    xp[i] = make_float4(v0, v1, v2, v0*v0 + v1*v1 + v2*v2);
  }
  unsigned int h0 = f2bf(v0), h1 = f2bf(v1), h2 = f2bf(v2);
  unsigned int l0 = f2bf(v0 - bf2f((unsigned short)h0));
  unsigned int l1 = f2bf(v1 - bf2f((unsigned short)h1));
  unsigned int l2 = f2bf(v2 - bf2f((unsigned short)h2));
  unsigned int ua0 = h0 | (h1<<16), ua1 = h2 | (l0<<16), ua2 = l1 | (l2<<16);
  unsigned int ub0 = h0 | (h1<<16), ub1 = h2 | (h0<<16), ub2 = h1 | (h2<<16);
  unsigned int ub3 = l0 | (l1<<16), ub4 = l2 | (l0<<16), ub5 = l1 | (l2<<16);
  uint4* pa = (uint4*)(xpa + (size_t)i*32);
  uint4* pb = (uint4*)(xpb + (size_t)i*32);
  uint4 z; z.x = 0u; z.y = 0u; z.z = 0u; z.w = 0u;
  uint4 A0; A0.x = ua0; A0.y = ua1; A0.z = ua2; A0.w = ua0;
  uint4 A1; A1.x = ua1; A1.y = ua2; A1.z = 0u;  A1.w = 0u;
  uint4 B0; B0.x = ub0; B0.y = ub1; B0.z = ub2; B0.w = ub3;
  uint4 B1; B1.x = ub4; B1.y = ub5; B1.z = 0u;  B1.w = 0u;
  pa[0] = A0; pa[1] = A1; pa[2] = z; pa[3] = z;
  pb[0] = B0; pb[1] = B1; pb[2] = z; pb[3] = z;
}

__global__ void sq64_kernel(const float* __restrict__ h, float* __restrict__ sq) {
  int i = blockIdx.x * blockDim.x + threadIdx.x;
  const float4* r = (const float4*)(h + (long)i*64);
  {
    #pragma clang fp contract(off)
    float ax=0.f, ay=0.f, az=0.f, aw=0.f;
    for (int t=0; t<16; t++) {
      float4 v = r[t];
      ax += v.x*v.x; ay += v.y*v.y; az += v.z*v.z; aw += v.w*v.w;
    }
    sq[i] = (ax+ay)+(az+aw);
  }
}

// ---------------- seed64: graph-1 neighbor bound, 4 lanes/query (R15-proven) ----------------
__global__ __launch_bounds__(256, 2) void seed64_kernel(const float* __restrict__ h,
                                                        const float* __restrict__ sq,
                                                        const int* __restrict__ idx1,
                                                        float* __restrict__ wsd) {
  int gid = blockIdx.x*256 + threadIdx.x;   // 65536
  int i = gid >> 2, part = gid & 3;
  float4 q4[16];
  const float4* qrow = (const float4*)(h + (size_t)i*64);
  #pragma unroll
  for (int t=0;t<16;t++) q4[t] = qrow[t];
  float sqi = sq[i];
  float wmax = 0.f;
  for (int k=part*5;k<part*5+5;k++) {
    int j = idx1[i*KNN+k];
    const float4* crow = (const float4*)(h + (size_t)j*64);
    float acc = 0.f;
    #pragma unroll 4
    for (int t=0;t<16;t++) {
      float4 c = crow[t];
      acc += q4[t].x*c.x; acc += q4[t].y*c.y; acc += q4[t].z*c.z; acc += q4[t].w*c.w;
    }
    float sqj = sq[j];
    float d = (sqi + sqj) - 2.0f*acc;
    d += (sqi + sqj)*3e-5f + 1e-25f;
    wmax = fmaxf(wmax, d);
  }
  wmax = fmaxf(wmax, __shfl_xor(wmax, 1));
  wmax = fmaxf(wmax, __shfl_xor(wmax, 2));
  if (part == 0) wsd[i] = wmax;
}

// register top-20: replace current lex-max with (e,ei), rescan for new max.
__device__ __forceinline__ void t20_replace_rescan(float (&rd)[KNN], int (&ri)[KNN],
                                                   float &maxd, int &maxi, int &maxp,
                                                   float e, int ei) {
  #pragma unroll
  for (int k = 0; k < KNN; k++) if (k == maxp) { rd[k] = e; ri[k] = ei; }
  float md = rd[0]; int mi = ri[0]; int mp = 0;
  #pragma unroll
  for (int k = 1; k < KNN; k++) {
    bool g = (rd[k] > md) || (rd[k] == md && ri[k] > mi);
    md = g ? rd[k] : md; mi = g ? ri[k] : mi; mp = g ? k : mp;
  }
  maxd = md; maxi = mi; maxp = mp;
}

// wave-internal fence: drain outstanding LDS ops + stop compiler reordering.
// NOTE: lgkmcnt only — global loads issued before this stay in flight (prefetch survives).
#define WAVE_LDS_FENCE() asm volatile("s_waitcnt lgkmcnt(0)" ::: "memory")

typedef __bf16 bf16x8 __attribute__((ext_vector_type(8)));
typedef float f32x4 __attribute__((ext_vector_type(4)));
#define MFMA16(A,B,C) __builtin_amdgcn_mfma_f32_16x16x32_bf16((A),(B),(C),0,0,0)
#define SCALE3 0.9998f
#define SCALE_HH 0.995f   // hi-only deflation: RNE bf16 product err <= 2^-8, 2x term < 0.4%

// bin an inflated distance; returns [0,63]
__device__ __forceinline__ int hbin(float uu) {
  uu = fmaxf(uu, 1e-20f);
  int b = (int)(__float_as_uint(uu) >> HBIN_SHIFT) - HBIN_BASE;
  return b < 0 ? 0 : (b > 63 ? 63 : b);
}

// ---------------- knn D=64: wsd-seeded hi-only MFMA filter + exact fp32 confirm ----------------
// R8/R13/R15-proven config: 2 waves/block, 32 queries/wave, 256-cand windows (16 tiles in
// 4 rolling 4-tile chunks). Queue: ushort candidate index; drain rescores EVERY survivor
// with the bit-identical exact fp32 fmaf chain (drains near-empty under the wsd seed).
__global__ __launch_bounds__(128, 2) void knn64_wq(const float* __restrict__ h1,
                                                   const unsigned short* __restrict__ hbh,
                                                   const float* __restrict__ sqh,
                                                   const float* __restrict__ wsd,
                                                   float* __restrict__ pd,
                                                   int* __restrict__ pi) {
  __shared__ unsigned short qq[2][32][QSW];
  __shared__ float w19[2][32];
  __shared__ int   cnt[2][32];

  int tid = threadIdx.x;
  int wv = tid >> 6;
  int l  = tid & 63;
  int qb = blockIdx.x >> 2, rg = blockIdx.x & 3;
  int q0 = qb*64, c0 = rg*C_RANGE;
  int qw0 = q0 + wv*32;

  float rd[KNN]; int ri[KNN];
  #pragma unroll
  for (int k = 0; k < KNN; k++) { rd[k] = INFINITY; ri[k] = 0x7fffffff; }
  float maxd = INFINITY; int maxi = 0x7fffffff; int maxp = 0;

  float wsv = INFINITY, sqi = 0.f;
  if (l < 32) {
    wsv = wsd[qw0 + l]; sqi = sqh[qw0 + l];
    w19[wv][l] = wsv; cnt[wv][l] = 0;
  }

  int cn   = l & 15;           // fragment row selector
  int koff = (l >> 4) * 8;     // k-offset within 32-wide K block

  bf16x8 a00, a01, a10, a11;   // A fragments: 2 query groups, hi-only
  {
    size_t ar = (size_t)(qw0 + cn) * 64 + koff;
    a00 = *(const bf16x8*)(hbh + ar);
    a01 = *(const bf16x8*)(hbh + ar + 32);
    size_t br = (size_t)(qw0 + 16 + cn) * 64 + koff;
    a10 = *(const bf16x8*)(hbh + br);
    a11 = *(const bf16x8*)(hbh + br + 32);
  }

  float qsl[8], wq[8];
  #pragma unroll
  for (int v = 0; v < 8; v++)
    qsl[v] = sqh[qw0 + (v>>2)*16 + (l>>4)*4 + (v&3)] * SCALE_HH;
  WAVE_LDS_FENCE();
  #pragma unroll
  for (int v = 0; v < 8; v++) wq[v] = w19[wv][(v>>2)*16 + (l>>4)*4 + (v&3)];

  bf16x8 Bp[8], Bq[8]; float Cp[4], Cq[4];   // ping-pong 4-tile chunks

  #define LOADC64(WIN, T0, B, C) do { int cw_ = c0 + (WIN)*256;            \
    _Pragma("unroll")                                                      \
    for (int t_ = 0; t_ < 4; t_++) {                                       \
      size_t br_ = (size_t)(cw_ + ((T0)+t_)*16 + cn) * 64 + koff;          \
      B[2*t_]   = *(const bf16x8*)(hbh + br_);                             \
      B[2*t_+1] = *(const bf16x8*)(hbh + br_ + 32);                        \
      C[t_] = sqh[cw_ + ((T0)+t_)*16 + cn];                                \
    } } while (0)

  #define TILE64(T, B0, B1, CS) do {                                       \
    f32x4 z_ = {0.f, 0.f, 0.f, 0.f};                                       \
    f32x4 d0_ = MFMA16(a00, B0, z_); d0_ = MFMA16(a01, B1, d0_);           \
    f32x4 d1_ = MFMA16(a10, B0, z_); d1_ = MFMA16(a11, B1, d1_);           \
    float csl_ = (CS) * SCALE_HH;                                          \
    _Pragma("unroll")                                                      \
    for (int v = 0; v < 8; v++) {                                          \
      float av_ = (v < 4) ? d0_[v] : d1_[v-4];                             \
      float dd_ = fmaf(-2.f, av_, qsl[v] + csl_);                          \
      if (dd_ <= wq[v]) {                                                  \
        int lq_ = (v>>2)*16 + (l>>4)*4 + (v&3);                            \
        int slot_ = atomicAdd(&cnt[wv][lq_], 1);                           \
        qq[wv][lq_][slot_] = (unsigned short)((T)*16 + cn);                \
      }                                                                    \
    } } while (0)

  #define CHUNK64(B, C, T0)                                                \
    TILE64((T0)+0, B[0], B[1], C[0]); TILE64((T0)+1, B[2], B[3], C[1]);    \
    TILE64((T0)+2, B[4], B[5], C[2]); TILE64((T0)+3, B[6], B[7], C[3])

  LOADC64(0, 0, Bp, Cp);
  for (int win = 0; win < C_RANGE/256; win++) {    // 16 windows
    int cw0 = c0 + win*256;
    LOADC64(win, 4, Bq, Cq);
    CHUNK64(Bp, Cp, 0);
    LOADC64(win, 8, Bp, Cp);
    CHUNK64(Bq, Cq, 4);
    LOADC64(win, 12, Bq, Cq);
    CHUNK64(Bp, Cp, 8);
    if (win < C_RANGE/256 - 1) LOADC64(win+1, 0, Bp, Cp);  // pre-fence prefetch
    CHUNK64(Bq, Cq, 12);

    WAVE_LDS_FENCE();
    int myc = (l < 32) ? cnt[wv][l] : 0;
    if (__any(myc != 0)) {
      if (myc) {
        const float4* qr = (const float4*)(h1 + (size_t)(qw0 + l)*64);
        for (int s = 0; s < myc; s++) {
          int j = cw0 + (int)qq[wv][l][s];
          const float4* cr = (const float4*)(h1 + (size_t)j*64);
          float a = 0.f;
          #pragma unroll 4
          for (int t = 0; t < 16; t++) {
            float4 q = qr[t], c = cr[t];
            a = fmaf(q.x, c.x, a); a = fmaf(q.y, c.y, a);
            a = fmaf(q.z, c.z, a); a = fmaf(q.w, c.w, a);
          }
          float e = (sqi + sqh[j]) - 2.0f*a;
          if (e < maxd || (e == maxd && j < maxi))
            t20_replace_rescan(rd, ri, maxd, maxi, maxp, e, j);
        }
        cnt[wv][l] = 0;
        w19[wv][l] = fminf(maxd, wsv);
      }
      WAVE_LDS_FENCE();
      #pragma unroll
      for (int v = 0; v < 8; v++) wq[v] = w19[wv][(v>>2)*16 + (l>>4)*4 + (v&3)];
    }
  }
  #undef LOADC64
  #undef TILE64
  #undef CHUNK64

  if (l < 32) {
    size_t o = ((size_t)(qw0 + l)*NRANGE + rg)*KNN;
    for (int k = 0; k < KNN; k++) {
      float md = rd[0]; int mi = ri[0]; int mp = 0;
      #pragma unroll
      for (int t = 1; t < KNN; t++) {
        bool g = (rd[t] < md) || (rd[t] == md && ri[t] < mi);
        md = g ? rd[t] : md; mi = g ? ri[t] : mi; mp = g ? t : mp;
      }
      pd[o+k] = md; pi[o+k] = mi;
      #pragma unroll
      for (int t = 0; t < KNN; t++) if (t == mp) rd[t] = INFINITY;
    }
  }
}

// ---------------- knn D=3: subsampled-hist seed + 256-cand-window pipelined scan ----------------
// R15-proven verbatim. Phase 1: bins INFLATED packed-MFMA distances of a 1024-cand
// subsample (windows 0,4,8,12) into per-query 64-bin log histograms (aliased on the queue
// LDS). cumsum>=20 => valid w0 upper bound of the range-20th. Phase 2: 256-cand windows;
// ushort queue; exact rescore drains.
__global__ __launch_bounds__(128, 2) void knn3_wq(const float4* __restrict__ xp,
                                                  const unsigned short* __restrict__ xpa,
                                                  const unsigned short* __restrict__ xpb,
                                                  float* __restrict__ pd,
                                                  int* __restrict__ pi) {
  __shared__ unsigned short qq[2][32][QSW];
  __shared__ float w19[2][32];
  __shared__ int   cnt[2][32];

  int tid = threadIdx.x;
  int wv = tid >> 6;
  int l  = tid & 63;
  int qb = blockIdx.x >> 2, rg = blockIdx.x & 3;
  int q0 = qb*64, c0 = rg*C_RANGE;
  int qw0 = q0 + wv*32;

  float rd[KNN]; int ri[KNN];
  #pragma unroll
  for (int k = 0; k < KNN; k++) { rd[k] = INFINITY; ri[k] = 0x7fffffff; }
  float maxd = INFINITY; int maxi = 0x7fffffff; int maxp = 0;

  float4 qv4 = make_float4(0.f, 0.f, 0.f, 0.f);
  if (l < 32) {
    cnt[wv][l] = 0;
    qv4 = xp[qw0 + l];
  }

  int cn   = l & 15;
  int koff = (l >> 4) * 8;

  bf16x8 aq0 = *(const bf16x8*)(xpa + (size_t)(qw0 + cn)*32 + koff);
  bf16x8 aq1 = *(const bf16x8*)(xpa + (size_t)(qw0 + 16 + cn)*32 + koff);

  float qsr[8], qsp[8];
  #pragma unroll
  for (int v = 0; v < 8; v++) {
    qsr[v] = xp[qw0 + (v>>2)*16 + (l>>4)*4 + (v&3)].w;
    qsp[v] = qsr[v] * SCALE3;
  }

  // ---- phase 1: subsampled histogram prologue (windows 0,4,8,12 = 1024 cands) ----
  unsigned int* hw = (unsigned int*)&qq[wv][0][0];   // [32][HQS] uints, per wave
  for (int t = l; t < 32*HQS; t += 64) hw[t] = 0u;
  WAVE_LDS_FENCE();

  for (int win = 0; win < 16; win += 4) {
    int cw0 = c0 + win*256;
    #pragma unroll
    for (int t = 0; t < 16; t++) {
      int ct = cw0 + t*16;
      bf16x8 bb = *(const bf16x8*)(xpb + (size_t)(ct + cn)*32 + koff);
      f32x4 z = {0.f, 0.f, 0.f, 0.f};
      f32x4 d0 = MFMA16(aq0, bb, z);
      f32x4 d1 = MFMA16(aq1, bb, z);
      float csr = xp[ct + cn].w;
      #pragma unroll
      for (int v = 0; v < 8; v++) {
        float av = (v < 4) ? d0[v] : d1[v-4];
        float uu = fmaf(-2.f, av, (qsr[v] + csr) * 1.0002f);  // >= exact distance
        int lq = (v>>2)*16 + (l>>4)*4 + (v&3);
        atomicAdd(&hw[lq*HQS + hbin(uu)], 1u);
      }
    }
  }
  WAVE_LDS_FENCE();

  float wsv = INFINITY;
  if (l < 32) {
    unsigned int c = 0; int bsel = 64;
    for (int b = 0; b < 64; b++) {
      c += hw[l*HQS + b];
      if (bsel == 64 && c >= 20u) bsel = b;
    }
    if (bsel < 63)
      wsv = __uint_as_float((unsigned int)(bsel + HBIN_BASE + 1) << HBIN_SHIFT);
  }
  WAVE_LDS_FENCE();          // all lanes done reading hw before queue reuse
  if (l < 32) {
    w19[wv][l] = wsv;
    cnt[wv][l] = 0;
  }
  WAVE_LDS_FENCE();
  float wq[8];
  #pragma unroll
  for (int v = 0; v < 8; v++) wq[v] = w19[wv][(v>>2)*16 + (l>>4)*4 + (v&3)];

  // ---- phase 2: pipelined main scan (256-cand windows, 4 rolling 4-tile chunks) ----
  bf16x8 Bp[4], Bq[4]; float Cp[4], Cq[4];

  #define LOADC3(WIN, T0, B, C) do { int cw_ = c0 + (WIN)*256;             \
    _Pragma("unroll")                                                      \
    for (int t_ = 0; t_ < 4; t_++) {                                       \
      int ct_ = cw_ + ((T0)+t_)*16;                                        \
      B[t_] = *(const bf16x8*)(xpb + (size_t)(ct_ + cn)*32 + koff);        \
      C[t_] = xp[ct_ + cn].w;                                              \
    } } while (0)

  #define TILE3(T, BB, CS) do {                                            \
    f32x4 z_ = {0.f, 0.f, 0.f, 0.f};                                       \
    f32x4 d0_ = MFMA16(aq0, BB, z_);                                       \
    f32x4 d1_ = MFMA16(aq1, BB, z_);                                       \
    float csp_ = (CS) * SCALE3;                                            \
    _Pragma("unroll")                                                      \
    for (int v = 0; v < 8; v++) {                                          \
      float av_ = (v < 4) ? d0_[v] : d1_[v-4];                             \
      float dd_ = fmaf(-2.f, av_, qsp[v] + csp_);                          \
      if (dd_ <= wq[v]) {                                                  \
        int lq_ = (v>>2)*16 + (l>>4)*4 + (v&3);                            \
        int slot_ = atomicAdd(&cnt[wv][lq_], 1);                           \
        qq[wv][lq_][slot_] = (unsigned short)((T)*16 + cn);                \
      }                                                                    \
    } } while (0)

  #define CHUNK3(B, C, T0)                                                 \
    TILE3((T0)+0, B[0], C[0]); TILE3((T0)+1, B[1], C[1]);                  \
    TILE3((T0)+2, B[2], C[2]); TILE3((T0)+3, B[3], C[3])

  LOADC3(0, 0, Bp, Cp);
  for (int win = 0; win < 16; win++) {
    int cw0 = c0 + win*256;
    LOADC3(win, 4, Bq, Cq);
    CHUNK3(Bp, Cp, 0);
    LOADC3(win, 8, Bp, Cp);
    CHUNK3(Bq, Cq, 4);
    LOADC3(win, 12, Bq, Cq);
    CHUNK3(Bp, Cp, 8);
    if (win < 15) LOADC3(win+1, 0, Bp, Cp);   // pre-fence prefetch
    CHUNK3(Bq, Cq, 12);

    WAVE_LDS_FENCE();
    int myc = (l < 32) ? cnt[wv][l] : 0;
    if (__any(myc != 0)) {
      if (myc) {
        for (int s = 0; s < myc; s++) {
          int j = cw0 + (int)qq[wv][l][s];
          float4 cv4 = xp[j];
          float e = (qv4.w + cv4.w)
                  - 2.0f*(qv4.x*cv4.x + qv4.y*cv4.y + qv4.z*cv4.z);
          if (e < maxd || (e == maxd && j < maxi))
            t20_replace_rescan(rd, ri, maxd, maxi, maxp, e, j);
        }
        cnt[wv][l] = 0;
        w19[wv][l] = fminf(maxd, wsv);
      }
      WAVE_LDS_FENCE();
      #pragma unroll
      for (int v = 0; v < 8; v++) wq[v] = w19[wv][(v>>2)*16 + (l>>4)*4 + (v&3)];
    }
  }
  #undef LOADC3
  #undef TILE3
  #undef CHUNK3

  if (l < 32) {
    size_t o = ((size_t)(qw0 + l)*NRANGE + rg)*KNN;
    for (int k = 0; k < KNN; k++) {
      float md = rd[0]; int mi = ri[0]; int mp = 0;
      #pragma unroll
      for (int t = 1; t < KNN; t++) {
        bool g = (rd[t] < md) || (rd[t] == md && ri[t] < mi);
        md = g ? rd[t] : md; mi = g ? ri[t] : mi; mp = g ? t : mp;
      }
      pd[o+k] = md; pi[o+k] = mi;
      #pragma unroll
      for (int t = 0; t < KNN; t++) if (t == mp) rd[t] = INFINITY;
    }
  }
}

// ---------------- merge NRANGE sorted partial lists -> top-20 (256 blocks: 1/CU) ----------
__global__ void knn_merge_kernel(const float* __restrict__ pd, const int* __restrict__ pi,
                                 int* __restrict__ out_idx) {
  int qi = blockIdx.x*64 + threadIdx.x;
  const float* bd = pd + (size_t)qi*NRANGE*KNN;
  const int*   bi = pi + (size_t)qi*NRANGE*KNN;
  int ptr[NRANGE];
  #pragma unroll
  for (int r=0;r<NRANGE;r++) ptr[r] = 0;
  for (int k = 0; k < KNN; k++) {
    float best = INFINITY; int besti = 0x7fffffff; int br = 0;
    #pragma unroll
    for (int r = 0; r < NRANGE; r++) {
      float d = bd[r*KNN + ptr[r]];
      int   ii = bi[r*KNN + ptr[r]];
      bool better = (ptr[r] < KNN) && (d < best || (d == best && ii < besti));
      if (better) { best = d; besti = ii; br = r; }
    }
    #pragma unroll
    for (int r=0;r<NRANGE;r++) ptr[r] += (r == br) ? 1 : 0;
    out_idx[qi*KNN + k] = besti;
  }
}

// ---------------- fused edge_conv1 + gather+max+relu + bf16-hi emit ----------------
// C1/G1 computed inline from x and W1 with the TEXTUALLY IDENTICAL expressions the old
// cg1_kernel used (same contraction -> bit-identical values); eliminates the cg1 launch
// and its 8.4MB intermediate write+read. W1/b1 are L1-resident (1.5KB).
__global__ void mrt64_kernel(const float* __restrict__ x, const float* __restrict__ W1,
                             const float* __restrict__ b1, const int* __restrict__ idx,
                             float* __restrict__ out, unsigned short* __restrict__ bh) {
  int gid = blockIdx.x*256 + threadIdx.x;   // 16384*16
  int i = gid >> 4, c4 = gid & 15;
  float wt0[4], wt1[4], wt2[4], wb0[4], wb1[4], wb2[4], bb[4];
  #pragma unroll
  for (int k = 0; k < 4; k++) {
    int c = c4*4 + k;
    wt0[k] = W1[0*64+c]; wt1[k] = W1[1*64+c]; wt2[k] = W1[2*64+c];
    wb0[k] = W1[3*64+c]; wb1[k] = W1[4*64+c]; wb2[k] = W1[5*64+c];
    bb[k]  = b1[c];
  }
  float x0 = x[i*3+0], x1 = x[i*3+1], x2 = x[i*3+2];
  float base[4], m[4];
  #pragma unroll
  for (int k = 0; k < 4; k++) {
    base[k] = x0*(wt0[k]-wb0[k]) + x1*(wt1[k]-wb1[k]) + x2*(wt2[k]-wb2[k]) + bb[k];
    m[k] = -INFINITY;
  }
  for (int j = 0; j < KNN; j++) {
    int jj = idx[i*KNN + j];
    float y0 = x[jj*3+0], y1 = x[jj*3+1], y2 = x[jj*3+2];
    #pragma unroll
    for (int k = 0; k < 4; k++) {
      float g = y0*wb0[k] + y1*wb1[k] + y2*wb2[k];
      m[k] = fmaxf(m[k], base[k] + g);
    }
  }
  float4 o;
  o.x = fmaxf(m[0], 0.0f); o.y = fmaxf(m[1], 0.0f);
  o.z = fmaxf(m[2], 0.0f); o.w = fmaxf(m[3], 0.0f);
  *(float4*)(out + (size_t)i*64 + c4*4) = o;
  ushort4 hv;
  hv.x = f2bf(o.x); hv.y = f2bf(o.y); hv.z = f2bf(o.z); hv.w = f2bf(o.w);
  ((ushort4*)bh)[i*16 + c4] = hv;
}

// ---------------- edge_conv2 precompute (wd2 fused inline, bit-identical) ----------------
__global__ void cg2_kernel(const float* __restrict__ h1, const float* __restrict__ W2,
                           const float* __restrict__ b2,
                           float* __restrict__ C2, float* __restrict__ G2) {
  int gid = blockIdx.x*256 + threadIdx.x;   // 16384*128
  int i = gid >> 7, c = gid & 127;
  float a = 0.f, g = 0.f;
  for (int d=0; d<64; d++) {
    float hv = h1[i*64 + d];
    float wt = W2[d*128 + c];
    float wb = W2[(d+64)*128 + c];
    a += hv * (wt - wb);
    g += hv * wb;
  }
  C2[gid] = a + b2[c];
  G2[gid] = g;
}

// ---------------- fused maxrelu(C=128) + fc1(relu) + fc2: one block per point ----------------
__global__ __launch_bounds__(128) void mrfc_kernel(const float* __restrict__ C2,
                                                   const float* __restrict__ G2,
                                                   const int* __restrict__ idx,
                                                   const float* __restrict__ w1,
                                                   const float* __restrict__ b1,
                                                   const float* __restrict__ w2,
                                                   const float* __restrict__ b2,
                                                   float* __restrict__ out) {
  __shared__ float h2r[128];
  __shared__ float f1r[128];
  int i = blockIdx.x, c = threadIdx.x;
  float base = C2[(size_t)i*128 + c];
  float m = -INFINITY;
  for (int j = 0; j < KNN; j++) {
    int jj = idx[i*KNN + j];
    m = fmaxf(m, base + G2[(size_t)jj*128 + c]);
  }
  h2r[c] = fmaxf(m, 0.0f);
  __syncthreads();
  float a = 0.f;
  for (int d = 0; d < 128; d++) a += h2r[d] * w1[d*128 + c];
  f1r[c] = fmaxf(a + b1[c], 0.0f);
  __syncthreads();
  if (c < 40) {
    float a2 = 0.f;
    for (int d = 0; d < 128; d++) a2 += f1r[d] * w2[d*40 + c];
    out[i*40 + c] = a2 + b2[c];
  }
}

extern "C" void kernel_launch(void* const* d_in, const int* in_sizes, int n_in,
                              void* d_out, int out_size, void* d_ws, size_t ws_size,
                              hipStream_t stream) {
  (void)in_sizes; (void)n_in; (void)out_size; (void)ws_size;
  const float* x     = (const float*)d_in[0];
  const float* W1    = (const float*)d_in[1];
  const float* b1    = (const float*)d_in[2];
  const float* W2    = (const float*)d_in[3];
  const float* b2    = (const float*)d_in[4];
  const float* fc1_w = (const float*)d_in[5];
  const float* fc1_b = (const float*)d_in[6];
  const float* fc2_w = (const float*)d_in[7];
  const float* fc2_b = (const float*)d_in[8];
  float* out = (float*)d_out;

  // ---- workspace (31.03 MB, lifetime-disjoint aliasing; R15 layout; C1/G1 eliminated) ----
  char* ws = (char*)d_ws;
  float4* xp4 = (float4*)(ws + 0);          // 262144
  float*  sqh = (float*) (ws + 262144);     // 65536
  int*    idx = (int*)   (ws + 327680);     // 1310720
  float*  h1  = (float*) (ws + 1671168);    // 4194304 -> 5865472
  unsigned short* xpa = (unsigned short*)(ws + 1671168); // 1MB, dead before h1 written
  unsigned short* xpb = (unsigned short*)(ws + 2719744); // 1MB, dead before h1 written
  unsigned short* hbh = (unsigned short*)(ws + 5865472); // 2097152 -> 7962624
  float*  wsd = (float*) (ws + 10059776);   // 65536
  float*  A   = (float*) (ws + 14254080);   // 8388608 -> 22642688
  float*  C2  = A;
  float*  G2  = (float*) (ws + 22642688);   // 8388608 -> 31031296
  int*    pi  = (int*)   (ws + 14254080);   // 5.25MB (aliases A; A dead during knn phases)
  float*  pd  = (float*) (ws + 22642688);   // 5.25MB (aliases G2; G2 dead during knn phases)

  pack_kernel  <<<64,    256, 0, stream>>>(x, xp4, xpa, xpb);
  knn3_wq      <<<1024,  128, 0, stream>>>(xp4, xpa, xpb, pd, pi);
  knn_merge_kernel<<<256, 64, 0, stream>>>(pd, pi, idx);
  mrt64_kernel <<<1024,  256, 0, stream>>>(x, W1, b1, idx, h1, hbh);
  sq64_kernel  <<<64,    256, 0, stream>>>(h1, sqh);
  seed64_kernel<<<256,   256, 0, stream>>>(h1, sqh, idx, wsd);
  knn64_wq     <<<1024,  128, 0, stream>>>(h1, hbh, sqh, wsd, pd, pi);
  knn_merge_kernel<<<256, 64, 0, stream>>>(pd, pi, idx);
  cg2_kernel   <<<8192,  256, 0, stream>>>(h1, W2, b2, C2, G2);
  mrfc_kernel  <<<16384, 128, 0, stream>>>(C2, G2, idx, fc1_w, fc1_b, fc2_w, fc2_b, out);
}

// Round 20
// 913.485 us; speedup vs baseline: 1.0902x; 1.0348x over previous
//
#include <hip/hip_runtime.h>
#include <math.h>

#define N_PTS 16384
#define KNN 20
#define NRANGE 4
#define C_RANGE (N_PTS / NRANGE)       // 4096
// both knn kernels: 256-cand windows (16 tiles), ushort index queues
#define QCAPW 256                       // structural: 16 lanes x 16 tiles
#define QSW 257                         // ushort queue stride
#define HQS 65                          // hist stride (uints): (65*lq+b)%32 = (lq+b)%32

// histogram binning: b = (bits(u)>>22) - 222  -> half-octave bins (ratio sqrt(2)),
// covering [2^-16, 2^16) in 64 bins. upper_edge(b) = as_float((b+223)<<22).
#define HBIN_SHIFT 22
#define HBIN_BASE 222

// ---------------- bf16 helpers ----------------
__device__ __forceinline__ unsigned short f2bf(float f) {
  unsigned int u = __float_as_uint(f);
  unsigned int r = (u + 0x7fffu + ((u >> 16) & 1u)) >> 16;   // round-to-nearest-even
  return (unsigned short)r;
}
__device__ __forceinline__ float bf2f(unsigned short b) {
  return __uint_as_float(((unsigned int)b) << 16);
}

// ---------------- pack x: float4+norm AND packed K=32 bf16 rows (fused; 1 block/CU) -----
// A-row: [qh0,qh1,qh2, ql0,ql1,ql2]x2, 0 pad.  B-row: [ch]x2,[cl]x2, 0 pad.
// => sum_k A[k]B[k] = (qh+ql).(ch+cl) exactly (all cross terms represented).
__global__ void pack_kernel(const float* __restrict__ x, float4* __restrict__ xp,
                            unsigned short* __restrict__ xpa,
                            unsigned short* __restrict__ xpb) {
  int i = blockIdx.x*64 + threadIdx.x;   // 16384 (256 blocks x 64)
  float v0 = x[i*3+0], v1 = x[i*3+1], v2 = x[i*3+2];
  {
    #pragma clang fp contract(off)
    xp[i] = make_float4(v0, v1, v2, v0*v0 + v1*v1 + v2*v2);
  }
  unsigned int h0 = f2bf(v0), h1 = f2bf(v1), h2 = f2bf(v2);
  unsigned int l0 = f2bf(v0 - bf2f((unsigned short)h0));
  unsigned int l1 = f2bf(v1 - bf2f((unsigned short)h1));
  unsigned int l2 = f2bf(v2 - bf2f((unsigned short)h2));
  unsigned int ua0 = h0 | (h1<<16), ua1 = h2 | (l0<<16), ua2 = l1 | (l2<<16);
  unsigned int ub0 = h0 | (h1<<16), ub1 = h2 | (h0<<16), ub2 = h1 | (h2<<16);
  unsigned int ub3 = l0 | (l1<<16), ub4 = l2 | (l0<<16), ub5 = l1 | (l2<<16);
  uint4* pa = (uint4*)(xpa + (size_t)i*32);
  uint4* pb = (uint4*)(xpb + (size_t)i*32);
  uint4 z; z.x = 0u; z.y = 0u; z.z = 0u; z.w = 0u;
  uint4 A0; A0.x = ua0; A0.y = ua1; A0.z = ua2; A0.w = ua0;
  uint4 A1; A1.x = ua1; A1.y = ua2; A1.z = 0u;  A1.w = 0u;
  uint4 B0; B0.x = ub0; B0.y = ub1; B0.z = ub2; B0.w = ub3;
  uint4 B1; B1.x = ub4; B1.y = ub5; B1.z = 0u;  B1.w = 0u;
  pa[0] = A0; pa[1] = A1; pa[2] = z; pa[3] = z;
  pb[0] = B0; pb[1] = B1; pb[2] = z; pb[3] = z;
}

__global__ void sq64_kernel(const float* __restrict__ h, float* __restrict__ sq) {
  int i = blockIdx.x*64 + threadIdx.x;   // 16384 (256 blocks x 64)
  const float4* r = (const float4*)(h + (long)i*64);
  {
    #pragma clang fp contract(off)
    float ax=0.f, ay=0.f, az=0.f, aw=0.f;
    for (int t=0; t<16; t++) {
      float4 v = r[t];
      ax += v.x*v.x; ay += v.y*v.y; az += v.z*v.z; aw += v.w*v.w;
    }
    sq[i] = (ax+ay)+(az+aw);
  }
}

// ---------------- seed64: graph-1 neighbor bound, 4 lanes/query (R15-proven) ----------------
__global__ __launch_bounds__(256, 2) void seed64_kernel(const float* __restrict__ h,
                                                        const float* __restrict__ sq,
                                                        const int* __restrict__ idx1,
                                                        float* __restrict__ wsd) {
  int gid = blockIdx.x*256 + threadIdx.x;   // 65536
  int i = gid >> 2, part = gid & 3;
  float4 q4[16];
  const float4* qrow = (const float4*)(h + (size_t)i*64);
  #pragma unroll
  for (int t=0;t<16;t++) q4[t] = qrow[t];
  float sqi = sq[i];
  float wmax = 0.f;
  for (int k=part*5;k<part*5+5;k++) {
    int j = idx1[i*KNN+k];
    const float4* crow = (const float4*)(h + (size_t)j*64);
    float acc = 0.f;
    #pragma unroll 4
    for (int t=0;t<16;t++) {
      float4 c = crow[t];
      acc += q4[t].x*c.x; acc += q4[t].y*c.y; acc += q4[t].z*c.z; acc += q4[t].w*c.w;
    }
    float sqj = sq[j];
    float d = (sqi + sqj) - 2.0f*acc;
    d += (sqi + sqj)*3e-5f + 1e-25f;
    wmax = fmaxf(wmax, d);
  }
  wmax = fmaxf(wmax, __shfl_xor(wmax, 1));
  wmax = fmaxf(wmax, __shfl_xor(wmax, 2));
  if (part == 0) wsd[i] = wmax;
}

// register top-20: replace current lex-max with (e,ei), rescan for new max.
__device__ __forceinline__ void t20_replace_rescan(float (&rd)[KNN], int (&ri)[KNN],
                                                   float &maxd, int &maxi, int &maxp,
                                                   float e, int ei) {
  #pragma unroll
  for (int k = 0; k < KNN; k++) if (k == maxp) { rd[k] = e; ri[k] = ei; }
  float md = rd[0]; int mi = ri[0]; int mp = 0;
  #pragma unroll
  for (int k = 1; k < KNN; k++) {
    bool g = (rd[k] > md) || (rd[k] == md && ri[k] > mi);
    md = g ? rd[k] : md; mi = g ? ri[k] : mi; mp = g ? k : mp;
  }
  maxd = md; maxi = mi; maxp = mp;
}

// wave-internal fence: drain outstanding LDS ops + stop compiler reordering.
// NOTE: lgkmcnt only — global loads issued before this stay in flight (prefetch survives).
#define WAVE_LDS_FENCE() asm volatile("s_waitcnt lgkmcnt(0)" ::: "memory")

typedef __bf16 bf16x8 __attribute__((ext_vector_type(8)));
typedef float f32x4 __attribute__((ext_vector_type(4)));
#define MFMA16(A,B,C) __builtin_amdgcn_mfma_f32_16x16x32_bf16((A),(B),(C),0,0,0)
#define SCALE3 0.9998f
#define SCALE_HH 0.995f   // hi-only deflation: RNE bf16 product err <= 2^-8, 2x term < 0.4%

// bin an inflated distance; returns [0,63]
__device__ __forceinline__ int hbin(float uu) {
  uu = fmaxf(uu, 1e-20f);
  int b = (int)(__float_as_uint(uu) >> HBIN_SHIFT) - HBIN_BASE;
  return b < 0 ? 0 : (b > 63 ? 63 : b);
}

// ---------------- knn D=64: wsd-seeded hi-only MFMA filter + exact fp32 confirm ----------------
// R8/R13/R15-proven config: 2 waves/block, 32 queries/wave, 256-cand windows (16 tiles in
// 4 rolling 4-tile chunks). Queue: ushort candidate index; drain rescores EVERY survivor
// with the bit-identical exact fp32 fmaf chain (drains near-empty under the wsd seed).
__global__ __launch_bounds__(128, 2) void knn64_wq(const float* __restrict__ h1,
                                                   const unsigned short* __restrict__ hbh,
                                                   const float* __restrict__ sqh,
                                                   const float* __restrict__ wsd,
                                                   float* __restrict__ pd,
                                                   int* __restrict__ pi) {
  __shared__ unsigned short qq[2][32][QSW];
  __shared__ float w19[2][32];
  __shared__ int   cnt[2][32];

  int tid = threadIdx.x;
  int wv = tid >> 6;
  int l  = tid & 63;
  int qb = blockIdx.x >> 2, rg = blockIdx.x & 3;
  int q0 = qb*64, c0 = rg*C_RANGE;
  int qw0 = q0 + wv*32;

  float rd[KNN]; int ri[KNN];
  #pragma unroll
  for (int k = 0; k < KNN; k++) { rd[k] = INFINITY; ri[k] = 0x7fffffff; }
  float maxd = INFINITY; int maxi = 0x7fffffff; int maxp = 0;

  float wsv = INFINITY, sqi = 0.f;
  if (l < 32) {
    wsv = wsd[qw0 + l]; sqi = sqh[qw0 + l];
    w19[wv][l] = wsv; cnt[wv][l] = 0;
  }

  int cn   = l & 15;           // fragment row selector
  int koff = (l >> 4) * 8;     // k-offset within 32-wide K block

  bf16x8 a00, a01, a10, a11;   // A fragments: 2 query groups, hi-only
  {
    size_t ar = (size_t)(qw0 + cn) * 64 + koff;
    a00 = *(const bf16x8*)(hbh + ar);
    a01 = *(const bf16x8*)(hbh + ar + 32);
    size_t br = (size_t)(qw0 + 16 + cn) * 64 + koff;
    a10 = *(const bf16x8*)(hbh + br);
    a11 = *(const bf16x8*)(hbh + br + 32);
  }

  float qsl[8], wq[8];
  #pragma unroll
  for (int v = 0; v < 8; v++)
    qsl[v] = sqh[qw0 + (v>>2)*16 + (l>>4)*4 + (v&3)] * SCALE_HH;
  WAVE_LDS_FENCE();
  #pragma unroll
  for (int v = 0; v < 8; v++) wq[v] = w19[wv][(v>>2)*16 + (l>>4)*4 + (v&3)];

  bf16x8 Bp[8], Bq[8]; float Cp[4], Cq[4];   // ping-pong 4-tile chunks

  #define LOADC64(WIN, T0, B, C) do { int cw_ = c0 + (WIN)*256;            \
    _Pragma("unroll")                                                      \
    for (int t_ = 0; t_ < 4; t_++) {                                       \
      size_t br_ = (size_t)(cw_ + ((T0)+t_)*16 + cn) * 64 + koff;          \
      B[2*t_]   = *(const bf16x8*)(hbh + br_);                             \
      B[2*t_+1] = *(const bf16x8*)(hbh + br_ + 32);                        \
      C[t_] = sqh[cw_ + ((T0)+t_)*16 + cn];                                \
    } } while (0)

  #define TILE64(T, B0, B1, CS) do {                                       \
    f32x4 z_ = {0.f, 0.f, 0.f, 0.f};                                       \
    f32x4 d0_ = MFMA16(a00, B0, z_); d0_ = MFMA16(a01, B1, d0_);           \
    f32x4 d1_ = MFMA16(a10, B0, z_); d1_ = MFMA16(a11, B1, d1_);           \
    float csl_ = (CS) * SCALE_HH;                                          \
    _Pragma("unroll")                                                      \
    for (int v = 0; v < 8; v++) {                                          \
      float av_ = (v < 4) ? d0_[v] : d1_[v-4];                             \
      float dd_ = fmaf(-2.f, av_, qsl[v] + csl_);                          \
      if (dd_ <= wq[v]) {                                                  \
        int lq_ = (v>>2)*16 + (l>>4)*4 + (v&3);                            \
        int slot_ = atomicAdd(&cnt[wv][lq_], 1);                           \
        qq[wv][lq_][slot_] = (unsigned short)((T)*16 + cn);                \
      }                                                                    \
    } } while (0)

  #define CHUNK64(B, C, T0)                                                \
    TILE64((T0)+0, B[0], B[1], C[0]); TILE64((T0)+1, B[2], B[3], C[1]);    \
    TILE64((T0)+2, B[4], B[5], C[2]); TILE64((T0)+3, B[6], B[7], C[3])

  LOADC64(0, 0, Bp, Cp);
  for (int win = 0; win < C_RANGE/256; win++) {    // 16 windows
    int cw0 = c0 + win*256;
    LOADC64(win, 4, Bq, Cq);
    CHUNK64(Bp, Cp, 0);
    LOADC64(win, 8, Bp, Cp);
    CHUNK64(Bq, Cq, 4);
    LOADC64(win, 12, Bq, Cq);
    CHUNK64(Bp, Cp, 8);
    if (win < C_RANGE/256 - 1) LOADC64(win+1, 0, Bp, Cp);  // pre-fence prefetch
    CHUNK64(Bq, Cq, 12);

    WAVE_LDS_FENCE();
    int myc = (l < 32) ? cnt[wv][l] : 0;
    if (__any(myc != 0)) {
      if (myc) {
        const float4* qr = (const float4*)(h1 + (size_t)(qw0 + l)*64);
        for (int s = 0; s < myc; s++) {
          int j = cw0 + (int)qq[wv][l][s];
          const float4* cr = (const float4*)(h1 + (size_t)j*64);
          float a = 0.f;
          #pragma unroll 4
          for (int t = 0; t < 16; t++) {
            float4 q = qr[t], c = cr[t];
            a = fmaf(q.x, c.x, a); a = fmaf(q.y, c.y, a);
            a = fmaf(q.z, c.z, a); a = fmaf(q.w, c.w, a);
          }
          float e = (sqi + sqh[j]) - 2.0f*a;
          if (e < maxd || (e == maxd && j < maxi))
            t20_replace_rescan(rd, ri, maxd, maxi, maxp, e, j);
        }
        cnt[wv][l] = 0;
        w19[wv][l] = fminf(maxd, wsv);
      }
      WAVE_LDS_FENCE();
      #pragma unroll
      for (int v = 0; v < 8; v++) wq[v] = w19[wv][(v>>2)*16 + (l>>4)*4 + (v&3)];
    }
  }
  #undef LOADC64
  #undef TILE64
  #undef CHUNK64

  if (l < 32) {
    size_t o = ((size_t)(qw0 + l)*NRANGE + rg)*KNN;
    for (int k = 0; k < KNN; k++) {
      float md = rd[0]; int mi = ri[0]; int mp = 0;
      #pragma unroll
      for (int t = 1; t < KNN; t++) {
        bool g = (rd[t] < md) || (rd[t] == md && ri[t] < mi);
        md = g ? rd[t] : md; mi = g ? ri[t] : mi; mp = g ? t : mp;
      }
      pd[o+k] = md; pi[o+k] = mi;
      #pragma unroll
      for (int t = 0; t < KNN; t++) if (t == mp) rd[t] = INFINITY;
    }
  }
}

// ---------------- knn D=3: subsampled-hist seed + 256-cand-window pipelined scan ----------------
// R15-proven verbatim. Phase 1: bins INFLATED packed-MFMA distances of a 1024-cand
// subsample (windows 0,4,8,12) into per-query 64-bin log histograms (aliased on the queue
// LDS). cumsum>=20 => valid w0 upper bound of the range-20th. Phase 2: 256-cand windows;
// ushort queue; exact rescore drains.
__global__ __launch_bounds__(128, 2) void knn3_wq(const float4* __restrict__ xp,
                                                  const unsigned short* __restrict__ xpa,
                                                  const unsigned short* __restrict__ xpb,
                                                  float* __restrict__ pd,
                                                  int* __restrict__ pi) {
  __shared__ unsigned short qq[2][32][QSW];
  __shared__ float w19[2][32];
  __shared__ int   cnt[2][32];

  int tid = threadIdx.x;
  int wv = tid >> 6;
  int l  = tid & 63;
  int qb = blockIdx.x >> 2, rg = blockIdx.x & 3;
  int q0 = qb*64, c0 = rg*C_RANGE;
  int qw0 = q0 + wv*32;

  float rd[KNN]; int ri[KNN];
  #pragma unroll
  for (int k = 0; k < KNN; k++) { rd[k] = INFINITY; ri[k] = 0x7fffffff; }
  float maxd = INFINITY; int maxi = 0x7fffffff; int maxp = 0;

  float4 qv4 = make_float4(0.f, 0.f, 0.f, 0.f);
  if (l < 32) {
    cnt[wv][l] = 0;
    qv4 = xp[qw0 + l];
  }

  int cn   = l & 15;
  int koff = (l >> 4) * 8;

  bf16x8 aq0 = *(const bf16x8*)(xpa + (size_t)(qw0 + cn)*32 + koff);
  bf16x8 aq1 = *(const bf16x8*)(xpa + (size_t)(qw0 + 16 + cn)*32 + koff);

  float qsr[8], qsp[8];
  #pragma unroll
  for (int v = 0; v < 8; v++) {
    qsr[v] = xp[qw0 + (v>>2)*16 + (l>>4)*4 + (v&3)].w;
    qsp[v] = qsr[v] * SCALE3;
  }

  // ---- phase 1: subsampled histogram prologue (windows 0,4,8,12 = 1024 cands) ----
  unsigned int* hw = (unsigned int*)&qq[wv][0][0];   // [32][HQS] uints, per wave
  for (int t = l; t < 32*HQS; t += 64) hw[t] = 0u;
  WAVE_LDS_FENCE();

  for (int win = 0; win < 16; win += 4) {
    int cw0 = c0 + win*256;
    #pragma unroll
    for (int t = 0; t < 16; t++) {
      int ct = cw0 + t*16;
      bf16x8 bb = *(const bf16x8*)(xpb + (size_t)(ct + cn)*32 + koff);
      f32x4 z = {0.f, 0.f, 0.f, 0.f};
      f32x4 d0 = MFMA16(aq0, bb, z);
      f32x4 d1 = MFMA16(aq1, bb, z);
      float csr = xp[ct + cn].w;
      #pragma unroll
      for (int v = 0; v < 8; v++) {
        float av = (v < 4) ? d0[v] : d1[v-4];
        float uu = fmaf(-2.f, av, (qsr[v] + csr) * 1.0002f);  // >= exact distance
        int lq = (v>>2)*16 + (l>>4)*4 + (v&3);
        atomicAdd(&hw[lq*HQS + hbin(uu)], 1u);
      }
    }
  }
  WAVE_LDS_FENCE();

  float wsv = INFINITY;
  if (l < 32) {
    unsigned int c = 0; int bsel = 64;
    for (int b = 0; b < 64; b++) {
      c += hw[l*HQS + b];
      if (bsel == 64 && c >= 20u) bsel = b;
    }
    if (bsel < 63)
      wsv = __uint_as_float((unsigned int)(bsel + HBIN_BASE + 1) << HBIN_SHIFT);
  }
  WAVE_LDS_FENCE();          // all lanes done reading hw before queue reuse
  if (l < 32) {
    w19[wv][l] = wsv;
    cnt[wv][l] = 0;
  }
  WAVE_LDS_FENCE();
  float wq[8];
  #pragma unroll
  for (int v = 0; v < 8; v++) wq[v] = w19[wv][(v>>2)*16 + (l>>4)*4 + (v&3)];

  // ---- phase 2: pipelined main scan (256-cand windows, 4 rolling 4-tile chunks) ----
  bf16x8 Bp[4], Bq[4]; float Cp[4], Cq[4];

  #define LOADC3(WIN, T0, B, C) do { int cw_ = c0 + (WIN)*256;             \
    _Pragma("unroll")                                                      \
    for (int t_ = 0; t_ < 4; t_++) {                                       \
      int ct_ = cw_ + ((T0)+t_)*16;                                        \
      B[t_] = *(const bf16x8*)(xpb + (size_t)(ct_ + cn)*32 + koff);        \
      C[t_] = xp[ct_ + cn].w;                                              \
    } } while (0)

  #define TILE3(T, BB, CS) do {                                            \
    f32x4 z_ = {0.f, 0.f, 0.f, 0.f};                                       \
    f32x4 d0_ = MFMA16(aq0, BB, z_);                                       \
    f32x4 d1_ = MFMA16(aq1, BB, z_);                                       \
    float csp_ = (CS) * SCALE3;                                            \
    _Pragma("unroll")                                                      \
    for (int v = 0; v < 8; v++) {                                          \
      float av_ = (v < 4) ? d0_[v] : d1_[v-4];                             \
      float dd_ = fmaf(-2.f, av_, qsp[v] + csp_);                          \
      if (dd_ <= wq[v]) {                                                  \
        int lq_ = (v>>2)*16 + (l>>4)*4 + (v&3);                            \
        int slot_ = atomicAdd(&cnt[wv][lq_], 1);                           \
        qq[wv][lq_][slot_] = (unsigned short)((T)*16 + cn);                \
      }                                                                    \
    } } while (0)

  #define CHUNK3(B, C, T0)                                                 \
    TILE3((T0)+0, B[0], C[0]); TILE3((T0)+1, B[1], C[1]);                  \
    TILE3((T0)+2, B[2], C[2]); TILE3((T0)+3, B[3], C[3])

  LOADC3(0, 0, Bp, Cp);
  for (int win = 0; win < 16; win++) {
    int cw0 = c0 + win*256;
    LOADC3(win, 4, Bq, Cq);
    CHUNK3(Bp, Cp, 0);
    LOADC3(win, 8, Bp, Cp);
    CHUNK3(Bq, Cq, 4);
    LOADC3(win, 12, Bq, Cq);
    CHUNK3(Bp, Cp, 8);
    if (win < 15) LOADC3(win+1, 0, Bp, Cp);   // pre-fence prefetch
    CHUNK3(Bq, Cq, 12);

    WAVE_LDS_FENCE();
    int myc = (l < 32) ? cnt[wv][l] : 0;
    if (__any(myc != 0)) {
      if (myc) {
        for (int s = 0; s < myc; s++) {
          int j = cw0 + (int)qq[wv][l][s];
          float4 cv4 = xp[j];
          float e = (qv4.w + cv4.w)
                  - 2.0f*(qv4.x*cv4.x + qv4.y*cv4.y + qv4.z*cv4.z);
          if (e < maxd || (e == maxd && j < maxi))
            t20_replace_rescan(rd, ri, maxd, maxi, maxp, e, j);
        }
        cnt[wv][l] = 0;
        w19[wv][l] = fminf(maxd, wsv);
      }
      WAVE_LDS_FENCE();
      #pragma unroll
      for (int v = 0; v < 8; v++) wq[v] = w19[wv][(v>>2)*16 + (l>>4)*4 + (v&3)];
    }
  }
  #undef LOADC3
  #undef TILE3
  #undef CHUNK3

  if (l < 32) {
    size_t o = ((size_t)(qw0 + l)*NRANGE + rg)*KNN;
    for (int k = 0; k < KNN; k++) {
      float md = rd[0]; int mi = ri[0]; int mp = 0;
      #pragma unroll
      for (int t = 1; t < KNN; t++) {
        bool g = (rd[t] < md) || (rd[t] == md && ri[t] < mi);
        md = g ? rd[t] : md; mi = g ? ri[t] : mi; mp = g ? t : mp;
      }
      pd[o+k] = md; pi[o+k] = mi;
      #pragma unroll
      for (int t = 0; t < KNN; t++) if (t == mp) rd[t] = INFINITY;
    }
  }
}

// ---------------- merge NRANGE sorted partial lists -> top-20 (256 blocks: 1/CU) ----------
__global__ void knn_merge_kernel(const float* __restrict__ pd, const int* __restrict__ pi,
                                 int* __restrict__ out_idx) {
  int qi = blockIdx.x*64 + threadIdx.x;
  const float* bd = pd + (size_t)qi*NRANGE*KNN;
  const int*   bi = pi + (size_t)qi*NRANGE*KNN;
  int ptr[NRANGE];
  #pragma unroll
  for (int r=0;r<NRANGE;r++) ptr[r] = 0;
  for (int k = 0; k < KNN; k++) {
    float best = INFINITY; int besti = 0x7fffffff; int br = 0;
    #pragma unroll
    for (int r = 0; r < NRANGE; r++) {
      float d = bd[r*KNN + ptr[r]];
      int   ii = bi[r*KNN + ptr[r]];
      bool better = (ptr[r] < KNN) && (d < best || (d == best && ii < besti));
      if (better) { best = d; besti = ii; br = r; }
    }
    #pragma unroll
    for (int r=0;r<NRANGE;r++) ptr[r] += (r == br) ? 1 : 0;
    out_idx[qi*KNN + k] = besti;
  }
}

// ---------------- fused edge_conv1 + gather+max+relu + bf16-hi emit (R19-proven) ----------
__global__ void mrt64_kernel(const float* __restrict__ x, const float* __restrict__ W1,
                             const float* __restrict__ b1, const int* __restrict__ idx,
                             float* __restrict__ out, unsigned short* __restrict__ bh) {
  int gid = blockIdx.x*256 + threadIdx.x;   // 16384*16
  int i = gid >> 4, c4 = gid & 15;
  float wt0[4], wt1[4], wt2[4], wb0[4], wb1[4], wb2[4], bb[4];
  #pragma unroll
  for (int k = 0; k < 4; k++) {
    int c = c4*4 + k;
    wt0[k] = W1[0*64+c]; wt1[k] = W1[1*64+c]; wt2[k] = W1[2*64+c];
    wb0[k] = W1[3*64+c]; wb1[k] = W1[4*64+c]; wb2[k] = W1[5*64+c];
    bb[k]  = b1[c];
  }
  float x0 = x[i*3+0], x1 = x[i*3+1], x2 = x[i*3+2];
  float base[4], m[4];
  #pragma unroll
  for (int k = 0; k < 4; k++) {
    base[k] = x0*(wt0[k]-wb0[k]) + x1*(wt1[k]-wb1[k]) + x2*(wt2[k]-wb2[k]) + bb[k];
    m[k] = -INFINITY;
  }
  for (int j = 0; j < KNN; j++) {
    int jj = idx[i*KNN + j];
    float y0 = x[jj*3+0], y1 = x[jj*3+1], y2 = x[jj*3+2];
    #pragma unroll
    for (int k = 0; k < 4; k++) {
      float g = y0*wb0[k] + y1*wb1[k] + y2*wb2[k];
      m[k] = fmaxf(m[k], base[k] + g);
    }
  }
  float4 o;
  o.x = fmaxf(m[0], 0.0f); o.y = fmaxf(m[1], 0.0f);
  o.z = fmaxf(m[2], 0.0f); o.w = fmaxf(m[3], 0.0f);
  *(float4*)(out + (size_t)i*64 + c4*4) = o;
  ushort4 hv;
  hv.x = f2bf(o.x); hv.y = f2bf(o.y); hv.z = f2bf(o.z); hv.w = f2bf(o.w);
  ((ushort4*)bh)[i*16 + c4] = hv;
}

// ---------------- edge_conv2 precompute (wd2 fused inline, bit-identical) ----------------
__global__ void cg2_kernel(const float* __restrict__ h1, const float* __restrict__ W2,
                           const float* __restrict__ b2,
                           float* __restrict__ C2, float* __restrict__ G2) {
  int gid = blockIdx.x*256 + threadIdx.x;   // 16384*128
  int i = gid >> 7, c = gid & 127;
  float a = 0.f, g = 0.f;
  for (int d=0; d<64; d++) {
    float hv = h1[i*64 + d];
    float wt = W2[d*128 + c];
    float wb = W2[(d+64)*128 + c];
    a += hv * (wt - wb);
    g += hv * wb;
  }
  C2[gid] = a + b2[c];
  G2[gid] = g;
}

// ---------------- fused maxrelu(C=128)+fc1+fc2, 4 points/block (weight reuse x4) ---------
// Per-point arithmetic identical to the 1-point version: d-ascending `a += h*w` chains,
// same fmax order. Loop restructure (load weight once, update 4 accumulators) only
// changes WHICH point uses the register copy -- each point's value chain is unchanged.
__global__ __launch_bounds__(128) void mrfc_kernel(const float* __restrict__ C2,
                                                   const float* __restrict__ G2,
                                                   const int* __restrict__ idx,
                                                   const float* __restrict__ w1,
                                                   const float* __restrict__ b1,
                                                   const float* __restrict__ w2,
                                                   const float* __restrict__ b2,
                                                   float* __restrict__ out) {
  __shared__ float h2r[4][128];
  __shared__ float f1r[4][128];
  int i0 = blockIdx.x*4, c = threadIdx.x;
  #pragma unroll
  for (int p = 0; p < 4; p++) {
    int i = i0 + p;
    float base = C2[(size_t)i*128 + c];
    float m = -INFINITY;
    for (int j = 0; j < KNN; j++) {
      int jj = idx[i*KNN + j];
      m = fmaxf(m, base + G2[(size_t)jj*128 + c]);
    }
    h2r[p][c] = fmaxf(m, 0.0f);
  }
  __syncthreads();
  float a[4] = {0.f, 0.f, 0.f, 0.f};
  for (int d = 0; d < 128; d++) {
    float wv = w1[d*128 + c];
    #pragma unroll
    for (int p = 0; p < 4; p++) a[p] += h2r[p][d] * wv;
  }
  #pragma unroll
  for (int p = 0; p < 4; p++) f1r[p][c] = fmaxf(a[p] + b1[c], 0.0f);
  __syncthreads();
  if (c < 40) {
    float a2[4] = {0.f, 0.f, 0.f, 0.f};
    for (int d = 0; d < 128; d++) {
      float wv = w2[d*40 + c];
      #pragma unroll
      for (int p = 0; p < 4; p++) a2[p] += f1r[p][d] * wv;
    }
    #pragma unroll
    for (int p = 0; p < 4; p++) out[(i0+p)*40 + c] = a2[p] + b2[c];
  }
}

extern "C" void kernel_launch(void* const* d_in, const int* in_sizes, int n_in,
                              void* d_out, int out_size, void* d_ws, size_t ws_size,
                              hipStream_t stream) {
  (void)in_sizes; (void)n_in; (void)out_size; (void)ws_size;
  const float* x     = (const float*)d_in[0];
  const float* W1    = (const float*)d_in[1];
  const float* b1    = (const float*)d_in[2];
  const float* W2    = (const float*)d_in[3];
  const float* b2    = (const float*)d_in[4];
  const float* fc1_w = (const float*)d_in[5];
  const float* fc1_b = (const float*)d_in[6];
  const float* fc2_w = (const float*)d_in[7];
  const float* fc2_b = (const float*)d_in[8];
  float* out = (float*)d_out;

  // ---- workspace (31.03 MB, lifetime-disjoint aliasing; R19 layout) ----
  char* ws = (char*)d_ws;
  float4* xp4 = (float4*)(ws + 0);          // 262144
  float*  sqh = (float*) (ws + 262144);     // 65536
  int*    idx = (int*)   (ws + 327680);     // 1310720
  float*  h1  = (float*) (ws + 1671168);    // 4194304 -> 5865472
  unsigned short* xpa = (unsigned short*)(ws + 1671168); // 1MB, dead before h1 written
  unsigned short* xpb = (unsigned short*)(ws + 2719744); // 1MB, dead before h1 written
  unsigned short* hbh = (unsigned short*)(ws + 5865472); // 2097152 -> 7962624
  float*  wsd = (float*) (ws + 10059776);   // 65536
  float*  A   = (float*) (ws + 14254080);   // 8388608 -> 22642688
  float*  C2  = A;
  float*  G2  = (float*) (ws + 22642688);   // 8388608 -> 31031296
  int*    pi  = (int*)   (ws + 14254080);   // 5.25MB (aliases A; A dead during knn phases)
  float*  pd  = (float*) (ws + 22642688);   // 5.25MB (aliases G2; G2 dead during knn phases)

  pack_kernel  <<<256,    64, 0, stream>>>(x, xp4, xpa, xpb);
  knn3_wq      <<<1024,  128, 0, stream>>>(xp4, xpa, xpb, pd, pi);
  knn_merge_kernel<<<256, 64, 0, stream>>>(pd, pi, idx);
  mrt64_kernel <<<1024,  256, 0, stream>>>(x, W1, b1, idx, h1, hbh);
  sq64_kernel  <<<256,    64, 0, stream>>>(h1, sqh);
  seed64_kernel<<<256,   256, 0, stream>>>(h1, sqh, idx, wsd);
  knn64_wq     <<<1024,  128, 0, stream>>>(h1, hbh, sqh, wsd, pd, pi);
  knn_merge_kernel<<<256, 64, 0, stream>>>(pd, pi, idx);
  cg2_kernel   <<<8192,  256, 0, stream>>>(h1, W2, b2, C2, G2);
  mrfc_kernel  <<<4096,  128, 0, stream>>>(C2, G2, idx, fc1_w, fc1_b, fc2_w, fc2_b, out);
}

// Round 22
// 887.254 us; speedup vs baseline: 1.1224x; 1.0296x over previous
//
#include <hip/hip_runtime.h>
#include <math.h>

#define N_PTS 16384
#define KNN 20
#define NRANGE 4
#define C_RANGE (N_PTS / NRANGE)       // 4096
// both knn kernels: 256-cand windows (16 tiles), ushort index queues
#define QCAPW 256                       // structural: 16 lanes x 16 tiles
#define QSW 257                         // ushort queue stride
#define HQS 65                          // hist stride (uints): (65*lq+b)%32 = (lq+b)%32

// histogram binning: b = (bits(u)>>22) - 222  -> half-octave bins (ratio sqrt(2)),
// covering [2^-16, 2^16) in 64 bins. upper_edge(b) = as_float((b+223)<<22).
#define HBIN_SHIFT 22
#define HBIN_BASE 222

// ---------------- bf16 helpers ----------------
__device__ __forceinline__ unsigned short f2bf(float f) {
  unsigned int u = __float_as_uint(f);
  unsigned int r = (u + 0x7fffu + ((u >> 16) & 1u)) >> 16;   // round-to-nearest-even
  return (unsigned short)r;
}
__device__ __forceinline__ float bf2f(unsigned short b) {
  return __uint_as_float(((unsigned int)b) << 16);
}

// ---------------- pack x: float4+norm AND packed K=32 bf16 rows (fused; 1 block/CU) -----
// A-row: [qh0,qh1,qh2, ql0,ql1,ql2]x2, 0 pad.  B-row: [ch]x2,[cl]x2, 0 pad.
// => sum_k A[k]B[k] = (qh+ql).(ch+cl) exactly (all cross terms represented).
__global__ void pack_kernel(const float* __restrict__ x, float4* __restrict__ xp,
                            unsigned short* __restrict__ xpa,
                            unsigned short* __restrict__ xpb) {
  int i = blockIdx.x*64 + threadIdx.x;   // 16384 (256 blocks x 64)
  float v0 = x[i*3+0], v1 = x[i*3+1], v2 = x[i*3+2];
  {
    #pragma clang fp contract(off)
    xp[i] = make_float4(v0, v1, v2, v0*v0 + v1*v1 + v2*v2);
  }
  unsigned int h0 = f2bf(v0), h1 = f2bf(v1), h2 = f2bf(v2);
  unsigned int l0 = f2bf(v0 - bf2f((unsigned short)h0));
  unsigned int l1 = f2bf(v1 - bf2f((unsigned short)h1));
  unsigned int l2 = f2bf(v2 - bf2f((unsigned short)h2));
  unsigned int ua0 = h0 | (h1<<16), ua1 = h2 | (l0<<16), ua2 = l1 | (l2<<16);
  unsigned int ub0 = h0 | (h1<<16), ub1 = h2 | (h0<<16), ub2 = h1 | (h2<<16);
  unsigned int ub3 = l0 | (l1<<16), ub4 = l2 | (l0<<16), ub5 = l1 | (l2<<16);
  uint4* pa = (uint4*)(xpa + (size_t)i*32);
  uint4* pb = (uint4*)(xpb + (size_t)i*32);
  uint4 z; z.x = 0u; z.y = 0u; z.z = 0u; z.w = 0u;
  uint4 A0; A0.x = ua0; A0.y = ua1; A0.z = ua2; A0.w = ua0;
  uint4 A1; A1.x = ua1; A1.y = ua2; A1.z = 0u;  A1.w = 0u;
  uint4 B0; B0.x = ub0; B0.y = ub1; B0.z = ub2; B0.w = ub3;
  uint4 B1; B1.x = ub4; B1.y = ub5; B1.z = 0u;  B1.w = 0u;
  pa[0] = A0; pa[1] = A1; pa[2] = z; pa[3] = z;
  pb[0] = B0; pb[1] = B1; pb[2] = z; pb[3] = z;
}

__global__ void sq64_kernel(const float* __restrict__ h, float* __restrict__ sq) {
  int i = blockIdx.x*64 + threadIdx.x;   // 16384 (256 blocks x 64)
  const float4* r = (const float4*)(h + (long)i*64);
  {
    #pragma clang fp contract(off)
    float ax=0.f, ay=0.f, az=0.f, aw=0.f;
    for (int t=0; t<16; t++) {
      float4 v = r[t];
      ax += v.x*v.x; ay += v.y*v.y; az += v.z*v.z; aw += v.w*v.w;
    }
    sq[i] = (ax+ay)+(az+aw);
  }
}

// ---------------- seed64: graph-1 neighbor bound, 4 lanes/query (R15-proven) ----------------
__global__ __launch_bounds__(256, 2) void seed64_kernel(const float* __restrict__ h,
                                                        const float* __restrict__ sq,
                                                        const int* __restrict__ idx1,
                                                        float* __restrict__ wsd) {
  int gid = blockIdx.x*256 + threadIdx.x;   // 65536
  int i = gid >> 2, part = gid & 3;
  float4 q4[16];
  const float4* qrow = (const float4*)(h + (size_t)i*64);
  #pragma unroll
  for (int t=0;t<16;t++) q4[t] = qrow[t];
  float sqi = sq[i];
  float wmax = 0.f;
  for (int k=part*5;k<part*5+5;k++) {
    int j = idx1[i*KNN+k];
    const float4* crow = (const float4*)(h + (size_t)j*64);
    float acc = 0.f;
    #pragma unroll 4
    for (int t=0;t<16;t++) {
      float4 c = crow[t];
      acc += q4[t].x*c.x; acc += q4[t].y*c.y; acc += q4[t].z*c.z; acc += q4[t].w*c.w;
    }
    float sqj = sq[j];
    float d = (sqi + sqj) - 2.0f*acc;
    d += (sqi + sqj)*3e-5f + 1e-25f;
    wmax = fmaxf(wmax, d);
  }
  wmax = fmaxf(wmax, __shfl_xor(wmax, 1));
  wmax = fmaxf(wmax, __shfl_xor(wmax, 2));
  if (part == 0) wsd[i] = wmax;
}

// register top-20: replace current lex-max with (e,ei), rescan for new max.
__device__ __forceinline__ void t20_replace_rescan(float (&rd)[KNN], int (&ri)[KNN],
                                                   float &maxd, int &maxi, int &maxp,
                                                   float e, int ei) {
  #pragma unroll
  for (int k = 0; k < KNN; k++) if (k == maxp) { rd[k] = e; ri[k] = ei; }
  float md = rd[0]; int mi = ri[0]; int mp = 0;
  #pragma unroll
  for (int k = 1; k < KNN; k++) {
    bool g = (rd[k] > md) || (rd[k] == md && ri[k] > mi);
    md = g ? rd[k] : md; mi = g ? ri[k] : mi; mp = g ? k : mp;
  }
  maxd = md; maxi = mi; maxp = mp;
}

// wave-internal fence: drain outstanding LDS ops + stop compiler reordering.
// NOTE: lgkmcnt only — global loads issued before this stay in flight (prefetch survives).
#define WAVE_LDS_FENCE() asm volatile("s_waitcnt lgkmcnt(0)" ::: "memory")

typedef __bf16 bf16x8 __attribute__((ext_vector_type(8)));
typedef float f32x4 __attribute__((ext_vector_type(4)));
#define MFMA16(A,B,C) __builtin_amdgcn_mfma_f32_16x16x32_bf16((A),(B),(C),0,0,0)
#define SCALE3 0.9998f
#define SCALE_HH 0.995f   // hi-only deflation: RNE bf16 product err <= 2^-8, 2x term < 0.4%

// bin an inflated distance; returns [0,63]
__device__ __forceinline__ int hbin(float uu) {
  uu = fmaxf(uu, 1e-20f);
  int b = (int)(__float_as_uint(uu) >> HBIN_SHIFT) - HBIN_BASE;
  return b < 0 ? 0 : (b > 63 ? 63 : b);
}

// ---------------- knn D=64: wsd-seeded hi-only MFMA filter + exact fp32 confirm ----------------
// R8/R13/R15-proven config: 2 waves/block, 32 queries/wave, 256-cand windows (16 tiles in
// 4 rolling 4-tile chunks). Queue: ushort candidate index; drain rescores EVERY survivor
// with the bit-identical exact fp32 fmaf chain (drains near-empty under the wsd seed).
__global__ __launch_bounds__(128, 2) void knn64_wq(const float* __restrict__ h1,
                                                   const unsigned short* __restrict__ hbh,
                                                   const float* __restrict__ sqh,
                                                   const float* __restrict__ wsd,
                                                   float* __restrict__ pd,
                                                   int* __restrict__ pi) {
  __shared__ unsigned short qq[2][32][QSW];
  __shared__ float w19[2][32];
  __shared__ int   cnt[2][32];

  int tid = threadIdx.x;
  int wv = tid >> 6;
  int l  = tid & 63;
  int qb = blockIdx.x >> 2, rg = blockIdx.x & 3;
  int q0 = qb*64, c0 = rg*C_RANGE;
  int qw0 = q0 + wv*32;

  float rd[KNN]; int ri[KNN];
  #pragma unroll
  for (int k = 0; k < KNN; k++) { rd[k] = INFINITY; ri[k] = 0x7fffffff; }
  float maxd = INFINITY; int maxi = 0x7fffffff; int maxp = 0;

  float wsv = INFINITY, sqi = 0.f;
  if (l < 32) {
    wsv = wsd[qw0 + l]; sqi = sqh[qw0 + l];
    w19[wv][l] = wsv; cnt[wv][l] = 0;
  }

  int cn   = l & 15;           // fragment row selector
  int koff = (l >> 4) * 8;     // k-offset within 32-wide K block

  bf16x8 a00, a01, a10, a11;   // A fragments: 2 query groups, hi-only
  {
    size_t ar = (size_t)(qw0 + cn) * 64 + koff;
    a00 = *(const bf16x8*)(hbh + ar);
    a01 = *(const bf16x8*)(hbh + ar + 32);
    size_t br = (size_t)(qw0 + 16 + cn) * 64 + koff;
    a10 = *(const bf16x8*)(hbh + br);
    a11 = *(const bf16x8*)(hbh + br + 32);
  }

  float qsl[8], wq[8];
  #pragma unroll
  for (int v = 0; v < 8; v++)
    qsl[v] = sqh[qw0 + (v>>2)*16 + (l>>4)*4 + (v&3)] * SCALE_HH;
  WAVE_LDS_FENCE();
  #pragma unroll
  for (int v = 0; v < 8; v++) wq[v] = w19[wv][(v>>2)*16 + (l>>4)*4 + (v&3)];

  bf16x8 Bp[8], Bq[8]; float Cp[4], Cq[4];   // ping-pong 4-tile chunks

  #define LOADC64(WIN, T0, B, C) do { int cw_ = c0 + (WIN)*256;            \
    _Pragma("unroll")                                                      \
    for (int t_ = 0; t_ < 4; t_++) {                                       \
      size_t br_ = (size_t)(cw_ + ((T0)+t_)*16 + cn) * 64 + koff;          \
      B[2*t_]   = *(const bf16x8*)(hbh + br_);                             \
      B[2*t_+1] = *(const bf16x8*)(hbh + br_ + 32);                        \
      C[t_] = sqh[cw_ + ((T0)+t_)*16 + cn];                                \
    } } while (0)

  #define TILE64(T, B0, B1, CS) do {                                       \
    f32x4 z_ = {0.f, 0.f, 0.f, 0.f};                                       \
    f32x4 d0_ = MFMA16(a00, B0, z_); d0_ = MFMA16(a01, B1, d0_);           \
    f32x4 d1_ = MFMA16(a10, B0, z_); d1_ = MFMA16(a11, B1, d1_);           \
    float csl_ = (CS) * SCALE_HH;                                          \
    _Pragma("unroll")                                                      \
    for (int v = 0; v < 8; v++) {                                          \
      float av_ = (v < 4) ? d0_[v] : d1_[v-4];                             \
      float dd_ = fmaf(-2.f, av_, qsl[v] + csl_);                          \
      if (dd_ <= wq[v]) {                                                  \
        int lq_ = (v>>2)*16 + (l>>4)*4 + (v&3);                            \
        int slot_ = atomicAdd(&cnt[wv][lq_], 1);                           \
        qq[wv][lq_][slot_] = (unsigned short)((T)*16 + cn);                \
      }                                                                    \
    } } while (0)

  #define CHUNK64(B, C, T0)                                                \
    TILE64((T0)+0, B[0], B[1], C[0]); TILE64((T0)+1, B[2], B[3], C[1]);    \
    TILE64((T0)+2, B[4], B[5], C[2]); TILE64((T0)+3, B[6], B[7], C[3])

  LOADC64(0, 0, Bp, Cp);
  for (int win = 0; win < C_RANGE/256; win++) {    // 16 windows
    int cw0 = c0 + win*256;
    LOADC64(win, 4, Bq, Cq);
    CHUNK64(Bp, Cp, 0);
    LOADC64(win, 8, Bp, Cp);
    CHUNK64(Bq, Cq, 4);
    LOADC64(win, 12, Bq, Cq);
    CHUNK64(Bp, Cp, 8);
    if (win < C_RANGE/256 - 1) LOADC64(win+1, 0, Bp, Cp);  // pre-fence prefetch
    CHUNK64(Bq, Cq, 12);

    WAVE_LDS_FENCE();
    int myc = (l < 32) ? cnt[wv][l] : 0;
    if (__any(myc != 0)) {
      if (myc) {
        const float4* qr = (const float4*)(h1 + (size_t)(qw0 + l)*64);
        for (int s = 0; s < myc; s++) {
          int j = cw0 + (int)qq[wv][l][s];
          const float4* cr = (const float4*)(h1 + (size_t)j*64);
          float a = 0.f;
          #pragma unroll 4
          for (int t = 0; t < 16; t++) {
            float4 q = qr[t], c = cr[t];
            a = fmaf(q.x, c.x, a); a = fmaf(q.y, c.y, a);
            a = fmaf(q.z, c.z, a); a = fmaf(q.w, c.w, a);
          }
          float e = (sqi + sqh[j]) - 2.0f*a;
          if (e < maxd || (e == maxd && j < maxi))
            t20_replace_rescan(rd, ri, maxd, maxi, maxp, e, j);
        }
        cnt[wv][l] = 0;
        w19[wv][l] = fminf(maxd, wsv);
      }
      WAVE_LDS_FENCE();
      #pragma unroll
      for (int v = 0; v < 8; v++) wq[v] = w19[wv][(v>>2)*16 + (l>>4)*4 + (v&3)];
    }
  }
  #undef LOADC64
  #undef TILE64
  #undef CHUNK64

  if (l < 32) {
    size_t o = ((size_t)(qw0 + l)*NRANGE + rg)*KNN;
    for (int k = 0; k < KNN; k++) {
      float md = rd[0]; int mi = ri[0]; int mp = 0;
      #pragma unroll
      for (int t = 1; t < KNN; t++) {
        bool g = (rd[t] < md) || (rd[t] == md && ri[t] < mi);
        md = g ? rd[t] : md; mi = g ? ri[t] : mi; mp = g ? t : mp;
      }
      pd[o+k] = md; pi[o+k] = mi;
      #pragma unroll
      for (int t = 0; t < KNN; t++) if (t == mp) rd[t] = INFINITY;
    }
  }
}

// ---------------- knn D=3: subsampled-hist seed + 256-cand-window pipelined scan ----------------
// R15-proven verbatim. Phase 1: bins INFLATED packed-MFMA distances of a 1024-cand
// subsample (windows 0,4,8,12) into per-query 64-bin log histograms (aliased on the queue
// LDS). cumsum>=20 => valid w0 upper bound of the range-20th. Phase 2: 256-cand windows;
// ushort queue; exact rescore drains.
__global__ __launch_bounds__(128, 2) void knn3_wq(const float4* __restrict__ xp,
                                                  const unsigned short* __restrict__ xpa,
                                                  const unsigned short* __restrict__ xpb,
                                                  float* __restrict__ pd,
                                                  int* __restrict__ pi) {
  __shared__ unsigned short qq[2][32][QSW];
  __shared__ float w19[2][32];
  __shared__ int   cnt[2][32];

  int tid = threadIdx.x;
  int wv = tid >> 6;
  int l  = tid & 63;
  int qb = blockIdx.x >> 2, rg = blockIdx.x & 3;
  int q0 = qb*64, c0 = rg*C_RANGE;
  int qw0 = q0 + wv*32;

  float rd[KNN]; int ri[KNN];
  #pragma unroll
  for (int k = 0; k < KNN; k++) { rd[k] = INFINITY; ri[k] = 0x7fffffff; }
  float maxd = INFINITY; int maxi = 0x7fffffff; int maxp = 0;

  float4 qv4 = make_float4(0.f, 0.f, 0.f, 0.f);
  if (l < 32) {
    cnt[wv][l] = 0;
    qv4 = xp[qw0 + l];
  }

  int cn   = l & 15;
  int koff = (l >> 4) * 8;

  bf16x8 aq0 = *(const bf16x8*)(xpa + (size_t)(qw0 + cn)*32 + koff);
  bf16x8 aq1 = *(const bf16x8*)(xpa + (size_t)(qw0 + 16 + cn)*32 + koff);

  float qsr[8], qsp[8];
  #pragma unroll
  for (int v = 0; v < 8; v++) {
    qsr[v] = xp[qw0 + (v>>2)*16 + (l>>4)*4 + (v&3)].w;
    qsp[v] = qsr[v] * SCALE3;
  }

  // ---- phase 1: subsampled histogram prologue (windows 0,4,8,12 = 1024 cands) ----
  unsigned int* hw = (unsigned int*)&qq[wv][0][0];   // [32][HQS] uints, per wave
  for (int t = l; t < 32*HQS; t += 64) hw[t] = 0u;
  WAVE_LDS_FENCE();

  for (int win = 0; win < 16; win += 4) {
    int cw0 = c0 + win*256;
    #pragma unroll
    for (int t = 0; t < 16; t++) {
      int ct = cw0 + t*16;
      bf16x8 bb = *(const bf16x8*)(xpb + (size_t)(ct + cn)*32 + koff);
      f32x4 z = {0.f, 0.f, 0.f, 0.f};
      f32x4 d0 = MFMA16(aq0, bb, z);
      f32x4 d1 = MFMA16(aq1, bb, z);
      float csr = xp[ct + cn].w;
      #pragma unroll
      for (int v = 0; v < 8; v++) {
        float av = (v < 4) ? d0[v] : d1[v-4];
        float uu = fmaf(-2.f, av, (qsr[v] + csr) * 1.0002f);  // >= exact distance
        int lq = (v>>2)*16 + (l>>4)*4 + (v&3);
        atomicAdd(&hw[lq*HQS + hbin(uu)], 1u);
      }
    }
  }
  WAVE_LDS_FENCE();

  float wsv = INFINITY;
  if (l < 32) {
    unsigned int c = 0; int bsel = 64;
    for (int b = 0; b < 64; b++) {
      c += hw[l*HQS + b];
      if (bsel == 64 && c >= 20u) bsel = b;
    }
    if (bsel < 63)
      wsv = __uint_as_float((unsigned int)(bsel + HBIN_BASE + 1) << HBIN_SHIFT);
  }
  WAVE_LDS_FENCE();          // all lanes done reading hw before queue reuse
  if (l < 32) {
    w19[wv][l] = wsv;
    cnt[wv][l] = 0;
  }
  WAVE_LDS_FENCE();
  float wq[8];
  #pragma unroll
  for (int v = 0; v < 8; v++) wq[v] = w19[wv][(v>>2)*16 + (l>>4)*4 + (v&3)];

  // ---- phase 2: pipelined main scan (256-cand windows, 4 rolling 4-tile chunks) ----
  bf16x8 Bp[4], Bq[4]; float Cp[4], Cq[4];

  #define LOADC3(WIN, T0, B, C) do { int cw_ = c0 + (WIN)*256;             \
    _Pragma("unroll")                                                      \
    for (int t_ = 0; t_ < 4; t_++) {                                       \
      int ct_ = cw_ + ((T0)+t_)*16;                                        \
      B[t_] = *(const bf16x8*)(xpb + (size_t)(ct_ + cn)*32 + koff);        \
      C[t_] = xp[ct_ + cn].w;                                              \
    } } while (0)

  #define TILE3(T, BB, CS) do {                                            \
    f32x4 z_ = {0.f, 0.f, 0.f, 0.f};                                       \
    f32x4 d0_ = MFMA16(aq0, BB, z_);                                       \
    f32x4 d1_ = MFMA16(aq1, BB, z_);                                       \
    float csp_ = (CS) * SCALE3;                                            \
    _Pragma("unroll")                                                      \
    for (int v = 0; v < 8; v++) {                                          \
      float av_ = (v < 4) ? d0_[v] : d1_[v-4];                             \
      float dd_ = fmaf(-2.f, av_, qsp[v] + csp_);                          \
      if (dd_ <= wq[v]) {                                                  \
        int lq_ = (v>>2)*16 + (l>>4)*4 + (v&3);                            \
        int slot_ = atomicAdd(&cnt[wv][lq_], 1);                           \
        qq[wv][lq_][slot_] = (unsigned short)((T)*16 + cn);                \
      }                                                                    \
    } } while (0)

  #define CHUNK3(B, C, T0)                                                 \
    TILE3((T0)+0, B[0], C[0]); TILE3((T0)+1, B[1], C[1]);                  \
    TILE3((T0)+2, B[2], C[2]); TILE3((T0)+3, B[3], C[3])

  LOADC3(0, 0, Bp, Cp);
  for (int win = 0; win < 16; win++) {
    int cw0 = c0 + win*256;
    LOADC3(win, 4, Bq, Cq);
    CHUNK3(Bp, Cp, 0);
    LOADC3(win, 8, Bp, Cp);
    CHUNK3(Bq, Cq, 4);
    LOADC3(win, 12, Bq, Cq);
    CHUNK3(Bp, Cp, 8);
    if (win < 15) LOADC3(win+1, 0, Bp, Cp);   // pre-fence prefetch
    CHUNK3(Bq, Cq, 12);

    WAVE_LDS_FENCE();
    int myc = (l < 32) ? cnt[wv][l] : 0;
    if (__any(myc != 0)) {
      if (myc) {
        for (int s = 0; s < myc; s++) {
          int j = cw0 + (int)qq[wv][l][s];
          float4 cv4 = xp[j];
          float e = (qv4.w + cv4.w)
                  - 2.0f*(qv4.x*cv4.x + qv4.y*cv4.y + qv4.z*cv4.z);
          if (e < maxd || (e == maxd && j < maxi))
            t20_replace_rescan(rd, ri, maxd, maxi, maxp, e, j);
        }
        cnt[wv][l] = 0;
        w19[wv][l] = fminf(maxd, wsv);
      }
      WAVE_LDS_FENCE();
      #pragma unroll
      for (int v = 0; v < 8; v++) wq[v] = w19[wv][(v>>2)*16 + (l>>4)*4 + (v&3)];
    }
  }
  #undef LOADC3
  #undef TILE3
  #undef CHUNK3

  if (l < 32) {
    size_t o = ((size_t)(qw0 + l)*NRANGE + rg)*KNN;
    for (int k = 0; k < KNN; k++) {
      float md = rd[0]; int mi = ri[0]; int mp = 0;
      #pragma unroll
      for (int t = 1; t < KNN; t++) {
        bool g = (rd[t] < md) || (rd[t] == md && ri[t] < mi);
        md = g ? rd[t] : md; mi = g ? ri[t] : mi; mp = g ? t : mp;
      }
      pd[o+k] = md; pi[o+k] = mi;
      #pragma unroll
      for (int t = 0; t < KNN; t++) if (t == mp) rd[t] = INFINITY;
    }
  }
}

// ---------------- merge NRANGE sorted partial lists -> top-20 (256 blocks: 1/CU) ----------
__global__ void knn_merge_kernel(const float* __restrict__ pd, const int* __restrict__ pi,
                                 int* __restrict__ out_idx) {
  int qi = blockIdx.x*64 + threadIdx.x;
  const float* bd = pd + (size_t)qi*NRANGE*KNN;
  const int*   bi = pi + (size_t)qi*NRANGE*KNN;
  int ptr[NRANGE];
  #pragma unroll
  for (int r=0;r<NRANGE;r++) ptr[r] = 0;
  for (int k = 0; k < KNN; k++) {
    float best = INFINITY; int besti = 0x7fffffff; int br = 0;
    #pragma unroll
    for (int r = 0; r < NRANGE; r++) {
      float d = bd[r*KNN + ptr[r]];
      int   ii = bi[r*KNN + ptr[r]];
      bool better = (ptr[r] < KNN) && (d < best || (d == best && ii < besti));
      if (better) { best = d; besti = ii; br = r; }
    }
    #pragma unroll
    for (int r=0;r<NRANGE;r++) ptr[r] += (r == br) ? 1 : 0;
    out_idx[qi*KNN + k] = besti;
  }
}

// ---------------- fused edge_conv1 + gather+max+relu + bf16-hi emit (R19-proven) ----------
__global__ void mrt64_kernel(const float* __restrict__ x, const float* __restrict__ W1,
                             const float* __restrict__ b1, const int* __restrict__ idx,
                             float* __restrict__ out, unsigned short* __restrict__ bh) {
  int gid = blockIdx.x*256 + threadIdx.x;   // 16384*16
  int i = gid >> 4, c4 = gid & 15;
  float wt0[4], wt1[4], wt2[4], wb0[4], wb1[4], wb2[4], bb[4];
  #pragma unroll
  for (int k = 0; k < 4; k++) {
    int c = c4*4 + k;
    wt0[k] = W1[0*64+c]; wt1[k] = W1[1*64+c]; wt2[k] = W1[2*64+c];
    wb0[k] = W1[3*64+c]; wb1[k] = W1[4*64+c]; wb2[k] = W1[5*64+c];
    bb[k]  = b1[c];
  }
  float x0 = x[i*3+0], x1 = x[i*3+1], x2 = x[i*3+2];
  float base[4], m[4];
  #pragma unroll
  for (int k = 0; k < 4; k++) {
    base[k] = x0*(wt0[k]-wb0[k]) + x1*(wt1[k]-wb1[k]) + x2*(wt2[k]-wb2[k]) + bb[k];
    m[k] = -INFINITY;
  }
  for (int j = 0; j < KNN; j++) {
    int jj = idx[i*KNN + j];
    float y0 = x[jj*3+0], y1 = x[jj*3+1], y2 = x[jj*3+2];
    #pragma unroll
    for (int k = 0; k < 4; k++) {
      float g = y0*wb0[k] + y1*wb1[k] + y2*wb2[k];
      m[k] = fmaxf(m[k], base[k] + g);
    }
  }
  float4 o;
  o.x = fmaxf(m[0], 0.0f); o.y = fmaxf(m[1], 0.0f);
  o.z = fmaxf(m[2], 0.0f); o.w = fmaxf(m[3], 0.0f);
  *(float4*)(out + (size_t)i*64 + c4*4) = o;
  ushort4 hv;
  hv.x = f2bf(o.x); hv.y = f2bf(o.y); hv.z = f2bf(o.z); hv.w = f2bf(o.w);
  ((ushort4*)bh)[i*16 + c4] = hv;
}

// ---------------- edge_conv2, 8 points/block (weight reuse x8; wd2 fused inline) ---------
// Per-point chains d-ascending with the identical `a += hv*(wt-wb)`, `g += hv*wb`
// expressions (wt-wb computed once per d -- same value, same rounding) -> bit-identical.
// h1 rows staged in LDS (2KB, broadcast reads). Weight L2 traffic: 512MB -> 128MB.
__global__ __launch_bounds__(128) void cg2_kernel(const float* __restrict__ h1,
                                                  const float* __restrict__ W2,
                                                  const float* __restrict__ b2,
                                                  float* __restrict__ C2,
                                                  float* __restrict__ G2) {
  __shared__ float h1s[8][64];
  int i0 = blockIdx.x*8, c = threadIdx.x;   // 2048 blocks x 128
  for (int t = c; t < 512; t += 128)
    h1s[t>>6][t&63] = h1[(size_t)(i0 + (t>>6))*64 + (t&63)];
  __syncthreads();
  float a[8] = {0.f,0.f,0.f,0.f,0.f,0.f,0.f,0.f};
  float g[8] = {0.f,0.f,0.f,0.f,0.f,0.f,0.f,0.f};
  for (int d = 0; d < 64; d++) {
    float wt = W2[d*128 + c];
    float wb = W2[(d+64)*128 + c];
    float wd = wt - wb;
    #pragma unroll
    for (int p = 0; p < 8; p++) {
      float hv = h1s[p][d];
      a[p] += hv * wd;
      g[p] += hv * wb;
    }
  }
  float bv = b2[c];
  #pragma unroll
  for (int p = 0; p < 8; p++) {
    C2[(size_t)(i0+p)*128 + c] = a[p] + bv;
    G2[(size_t)(i0+p)*128 + c] = g[p];
  }
}

// ---------------- fused maxrelu(C=128)+fc1+fc2, 8 points/block (weight reuse x8) ---------
// Per-point arithmetic identical to the 1-point version: d-ascending `a += h*w` chains,
// same fmax order. Loop restructure only changes WHICH point uses the register copy.
__global__ __launch_bounds__(128) void mrfc_kernel(const float* __restrict__ C2,
                                                   const float* __restrict__ G2,
                                                   const int* __restrict__ idx,
                                                   const float* __restrict__ w1,
                                                   const float* __restrict__ b1,
                                                   const float* __restrict__ w2,
                                                   const float* __restrict__ b2,
                                                   float* __restrict__ out) {
  __shared__ float h2r[8][128];
  __shared__ float f1r[8][128];
  int i0 = blockIdx.x*8, c = threadIdx.x;   // 2048 blocks x 128
  #pragma unroll
  for (int p = 0; p < 8; p++) {
    int i = i0 + p;
    float base = C2[(size_t)i*128 + c];
    float m = -INFINITY;
    for (int j = 0; j < KNN; j++) {
      int jj = idx[i*KNN + j];
      m = fmaxf(m, base + G2[(size_t)jj*128 + c]);
    }
    h2r[p][c] = fmaxf(m, 0.0f);
  }
  __syncthreads();
  float a[8] = {0.f,0.f,0.f,0.f,0.f,0.f,0.f,0.f};
  for (int d = 0; d < 128; d++) {
    float wv = w1[d*128 + c];
    #pragma unroll
    for (int p = 0; p < 8; p++) a[p] += h2r[p][d] * wv;
  }
  float b1v = b1[c];
  #pragma unroll
  for (int p = 0; p < 8; p++) f1r[p][c] = fmaxf(a[p] + b1v, 0.0f);
  __syncthreads();
  if (c < 40) {
    float a2[8] = {0.f,0.f,0.f,0.f,0.f,0.f,0.f,0.f};
    for (int d = 0; d < 128; d++) {
      float wv = w2[d*40 + c];
      #pragma unroll
      for (int p = 0; p < 8; p++) a2[p] += f1r[p][d] * wv;
    }
    float b2v = b2[c];
    #pragma unroll
    for (int p = 0; p < 8; p++) out[(i0+p)*40 + c] = a2[p] + b2v;
  }
}

extern "C" void kernel_launch(void* const* d_in, const int* in_sizes, int n_in,
                              void* d_out, int out_size, void* d_ws, size_t ws_size,
                              hipStream_t stream) {
  (void)in_sizes; (void)n_in; (void)out_size; (void)ws_size;
  const float* x     = (const float*)d_in[0];
  const float* W1    = (const float*)d_in[1];
  const float* b1    = (const float*)d_in[2];
  const float* W2    = (const float*)d_in[3];
  const float* b2    = (const float*)d_in[4];
  const float* fc1_w = (const float*)d_in[5];
  const float* fc1_b = (const float*)d_in[6];
  const float* fc2_w = (const float*)d_in[7];
  const float* fc2_b = (const float*)d_in[8];
  float* out = (float*)d_out;

  // ---- workspace (31.03 MB, lifetime-disjoint aliasing; R19 layout) ----
  char* ws = (char*)d_ws;
  float4* xp4 = (float4*)(ws + 0);          // 262144
  float*  sqh = (float*) (ws + 262144);     // 65536
  int*    idx = (int*)   (ws + 327680);     // 1310720
  float*  h1  = (float*) (ws + 1671168);    // 4194304 -> 5865472
  unsigned short* xpa = (unsigned short*)(ws + 1671168); // 1MB, dead before h1 written
  unsigned short* xpb = (unsigned short*)(ws + 2719744); // 1MB, dead before h1 written
  unsigned short* hbh = (unsigned short*)(ws + 5865472); // 2097152 -> 7962624
  float*  wsd = (float*) (ws + 10059776);   // 65536
  float*  A   = (float*) (ws + 14254080);   // 8388608 -> 22642688
  float*  C2  = A;
  float*  G2  = (float*) (ws + 22642688);   // 8388608 -> 31031296
  int*    pi  = (int*)   (ws + 14254080);   // 5.25MB (aliases A; A dead during knn phases)
  float*  pd  = (float*) (ws + 22642688);   // 5.25MB (aliases G2; G2 dead during knn phases)

  pack_kernel  <<<256,    64, 0, stream>>>(x, xp4, xpa, xpb);
  knn3_wq      <<<1024,  128, 0, stream>>>(xp4, xpa, xpb, pd, pi);
  knn_merge_kernel<<<256, 64, 0, stream>>>(pd, pi, idx);
  mrt64_kernel <<<1024,  256, 0, stream>>>(x, W1, b1, idx, h1, hbh);
  sq64_kernel  <<<256,    64, 0, stream>>>(h1, sqh);
  seed64_kernel<<<256,   256, 0, stream>>>(h1, sqh, idx, wsd);
  knn64_wq     <<<1024,  128, 0, stream>>>(h1, hbh, sqh, wsd, pd, pi);
  knn_merge_kernel<<<256, 64, 0, stream>>>(pd, pi, idx);
  cg2_kernel   <<<2048,  128, 0, stream>>>(h1, W2, b2, C2, G2);
  mrfc_kernel  <<<2048,  128, 0, stream>>>(C2, G2, idx, fc1_w, fc1_b, fc2_w, fc2_b, out);
}

// Round 23
// 886.022 us; speedup vs baseline: 1.1240x; 1.0014x over previous
//
#include <hip/hip_runtime.h>
#include <math.h>

#define N_PTS 16384
#define KNN 20
#define NRANGE 4
#define C_RANGE (N_PTS / NRANGE)       // 4096
// both knn kernels: 256-cand windows (16 tiles), ushort index queues
#define QCAPW 256                       // structural: 16 lanes x 16 tiles
#define QSW 257                         // ushort queue stride
#define HQS 65                          // hist stride (uints): (65*lq+b)%32 = (lq+b)%32

// histogram binning: b = (bits(u)>>22) - 222  -> half-octave bins (ratio sqrt(2)),
// covering [2^-16, 2^16) in 64 bins. upper_edge(b) = as_float((b+223)<<22).
#define HBIN_SHIFT 22
#define HBIN_BASE 222

// ---------------- bf16 helpers ----------------
__device__ __forceinline__ unsigned short f2bf(float f) {
  unsigned int u = __float_as_uint(f);
  unsigned int r = (u + 0x7fffu + ((u >> 16) & 1u)) >> 16;   // round-to-nearest-even
  return (unsigned short)r;
}
__device__ __forceinline__ float bf2f(unsigned short b) {
  return __uint_as_float(((unsigned int)b) << 16);
}

// ---------------- pack x: float4+norm AND packed K=32 bf16 rows (fused; 1 block/CU) -----
// A-row: [qh0,qh1,qh2, ql0,ql1,ql2]x2, 0 pad.  B-row: [ch]x2,[cl]x2, 0 pad.
// => sum_k A[k]B[k] = (qh+ql).(ch+cl) exactly (all cross terms represented).
__global__ void pack_kernel(const float* __restrict__ x, float4* __restrict__ xp,
                            unsigned short* __restrict__ xpa,
                            unsigned short* __restrict__ xpb) {
  int i = blockIdx.x*64 + threadIdx.x;   // 16384 (256 blocks x 64)
  float v0 = x[i*3+0], v1 = x[i*3+1], v2 = x[i*3+2];
  {
    #pragma clang fp contract(off)
    xp[i] = make_float4(v0, v1, v2, v0*v0 + v1*v1 + v2*v2);
  }
  unsigned int h0 = f2bf(v0), h1 = f2bf(v1), h2 = f2bf(v2);
  unsigned int l0 = f2bf(v0 - bf2f((unsigned short)h0));
  unsigned int l1 = f2bf(v1 - bf2f((unsigned short)h1));
  unsigned int l2 = f2bf(v2 - bf2f((unsigned short)h2));
  unsigned int ua0 = h0 | (h1<<16), ua1 = h2 | (l0<<16), ua2 = l1 | (l2<<16);
  unsigned int ub0 = h0 | (h1<<16), ub1 = h2 | (h0<<16), ub2 = h1 | (h2<<16);
  unsigned int ub3 = l0 | (l1<<16), ub4 = l2 | (l0<<16), ub5 = l1 | (l2<<16);
  uint4* pa = (uint4*)(xpa + (size_t)i*32);
  uint4* pb = (uint4*)(xpb + (size_t)i*32);
  uint4 z; z.x = 0u; z.y = 0u; z.z = 0u; z.w = 0u;
  uint4 A0; A0.x = ua0; A0.y = ua1; A0.z = ua2; A0.w = ua0;
  uint4 A1; A1.x = ua1; A1.y = ua2; A1.z = 0u;  A1.w = 0u;
  uint4 B0; B0.x = ub0; B0.y = ub1; B0.z = ub2; B0.w = ub3;
  uint4 B1; B1.x = ub4; B1.y = ub5; B1.z = 0u;  B1.w = 0u;
  pa[0] = A0; pa[1] = A1; pa[2] = z; pa[3] = z;
  pb[0] = B0; pb[1] = B1; pb[2] = z; pb[3] = z;
}

__global__ void sq64_kernel(const float* __restrict__ h, float* __restrict__ sq) {
  int i = blockIdx.x*64 + threadIdx.x;   // 16384 (256 blocks x 64)
  const float4* r = (const float4*)(h + (long)i*64);
  {
    #pragma clang fp contract(off)
    float ax=0.f, ay=0.f, az=0.f, aw=0.f;
    for (int t=0; t<16; t++) {
      float4 v = r[t];
      ax += v.x*v.x; ay += v.y*v.y; az += v.z*v.z; aw += v.w*v.w;
    }
    sq[i] = (ax+ay)+(az+aw);
  }
}

// ---------------- seed64: graph-1 neighbor bound, 4 lanes/query (R15-proven) ----------------
__global__ __launch_bounds__(256, 2) void seed64_kernel(const float* __restrict__ h,
                                                        const float* __restrict__ sq,
                                                        const int* __restrict__ idx1,
                                                        float* __restrict__ wsd) {
  int gid = blockIdx.x*256 + threadIdx.x;   // 65536
  int i = gid >> 2, part = gid & 3;
  float4 q4[16];
  const float4* qrow = (const float4*)(h + (size_t)i*64);
  #pragma unroll
  for (int t=0;t<16;t++) q4[t] = qrow[t];
  float sqi = sq[i];
  float wmax = 0.f;
  for (int k=part*5;k<part*5+5;k++) {
    int j = idx1[i*KNN+k];
    const float4* crow = (const float4*)(h + (size_t)j*64);
    float acc = 0.f;
    #pragma unroll 4
    for (int t=0;t<16;t++) {
      float4 c = crow[t];
      acc += q4[t].x*c.x; acc += q4[t].y*c.y; acc += q4[t].z*c.z; acc += q4[t].w*c.w;
    }
    float sqj = sq[j];
    float d = (sqi + sqj) - 2.0f*acc;
    d += (sqi + sqj)*3e-5f + 1e-25f;
    wmax = fmaxf(wmax, d);
  }
  wmax = fmaxf(wmax, __shfl_xor(wmax, 1));
  wmax = fmaxf(wmax, __shfl_xor(wmax, 2));
  if (part == 0) wsd[i] = wmax;
}

// register top-20: replace current lex-max with (e,ei), rescan for new max.
__device__ __forceinline__ void t20_replace_rescan(float (&rd)[KNN], int (&ri)[KNN],
                                                   float &maxd, int &maxi, int &maxp,
                                                   float e, int ei) {
  #pragma unroll
  for (int k = 0; k < KNN; k++) if (k == maxp) { rd[k] = e; ri[k] = ei; }
  float md = rd[0]; int mi = ri[0]; int mp = 0;
  #pragma unroll
  for (int k = 1; k < KNN; k++) {
    bool g = (rd[k] > md) || (rd[k] == md && ri[k] > mi);
    md = g ? rd[k] : md; mi = g ? ri[k] : mi; mp = g ? k : mp;
  }
  maxd = md; maxi = mi; maxp = mp;
}

// wave-internal fence: drain outstanding LDS ops + stop compiler reordering.
// NOTE: lgkmcnt only — global loads issued before this stay in flight (prefetch survives).
#define WAVE_LDS_FENCE() asm volatile("s_waitcnt lgkmcnt(0)" ::: "memory")

typedef __bf16 bf16x8 __attribute__((ext_vector_type(8)));
typedef float f32x4 __attribute__((ext_vector_type(4)));
#define MFMA16(A,B,C) __builtin_amdgcn_mfma_f32_16x16x32_bf16((A),(B),(C),0,0,0)
#define SCALE3 0.9998f
#define SCALE_HH 0.995f   // hi-only deflation: RNE bf16 product err <= 2^-8, 2x term < 0.4%

// bin an inflated distance; returns [0,63]
__device__ __forceinline__ int hbin(float uu) {
  uu = fmaxf(uu, 1e-20f);
  int b = (int)(__float_as_uint(uu) >> HBIN_SHIFT) - HBIN_BASE;
  return b < 0 ? 0 : (b > 63 ? 63 : b);
}

// ---------------- knn D=64: wsd-seeded hi-only MFMA filter + exact fp32 confirm ----------------
// R8/R13/R15-proven config: 2 waves/block, 32 queries/wave, 256-cand windows (16 tiles in
// 4 rolling 4-tile chunks). Queue: ushort candidate index; drain rescores EVERY survivor
// with the bit-identical exact fp32 fmaf chain (drains near-empty under the wsd seed).
__global__ __launch_bounds__(128, 2) void knn64_wq(const float* __restrict__ h1,
                                                   const unsigned short* __restrict__ hbh,
                                                   const float* __restrict__ sqh,
                                                   const float* __restrict__ wsd,
                                                   float* __restrict__ pd,
                                                   int* __restrict__ pi) {
  __shared__ unsigned short qq[2][32][QSW];
  __shared__ float w19[2][32];
  __shared__ int   cnt[2][32];

  int tid = threadIdx.x;
  int wv = tid >> 6;
  int l  = tid & 63;
  int qb = blockIdx.x >> 2, rg = blockIdx.x & 3;
  int q0 = qb*64, c0 = rg*C_RANGE;
  int qw0 = q0 + wv*32;

  float rd[KNN]; int ri[KNN];
  #pragma unroll
  for (int k = 0; k < KNN; k++) { rd[k] = INFINITY; ri[k] = 0x7fffffff; }
  float maxd = INFINITY; int maxi = 0x7fffffff; int maxp = 0;

  float wsv = INFINITY, sqi = 0.f;
  if (l < 32) {
    wsv = wsd[qw0 + l]; sqi = sqh[qw0 + l];
    w19[wv][l] = wsv; cnt[wv][l] = 0;
  }

  int cn   = l & 15;           // fragment row selector
  int koff = (l >> 4) * 8;     // k-offset within 32-wide K block

  bf16x8 a00, a01, a10, a11;   // A fragments: 2 query groups, hi-only
  {
    size_t ar = (size_t)(qw0 + cn) * 64 + koff;
    a00 = *(const bf16x8*)(hbh + ar);
    a01 = *(const bf16x8*)(hbh + ar + 32);
    size_t br = (size_t)(qw0 + 16 + cn) * 64 + koff;
    a10 = *(const bf16x8*)(hbh + br);
    a11 = *(const bf16x8*)(hbh + br + 32);
  }

  float qsl[8], wq[8];
  #pragma unroll
  for (int v = 0; v < 8; v++)
    qsl[v] = sqh[qw0 + (v>>2)*16 + (l>>4)*4 + (v&3)] * SCALE_HH;
  WAVE_LDS_FENCE();
  #pragma unroll
  for (int v = 0; v < 8; v++) wq[v] = w19[wv][(v>>2)*16 + (l>>4)*4 + (v&3)];

  bf16x8 Bp[8], Bq[8]; float Cp[4], Cq[4];   // ping-pong 4-tile chunks

  #define LOADC64(WIN, T0, B, C) do { int cw_ = c0 + (WIN)*256;            \
    _Pragma("unroll")                                                      \
    for (int t_ = 0; t_ < 4; t_++) {                                       \
      size_t br_ = (size_t)(cw_ + ((T0)+t_)*16 + cn) * 64 + koff;          \
      B[2*t_]   = *(const bf16x8*)(hbh + br_);                             \
      B[2*t_+1] = *(const bf16x8*)(hbh + br_ + 32);                        \
      C[t_] = sqh[cw_ + ((T0)+t_)*16 + cn];                                \
    } } while (0)

  #define TILE64(T, B0, B1, CS) do {                                       \
    f32x4 z_ = {0.f, 0.f, 0.f, 0.f};                                       \
    f32x4 d0_ = MFMA16(a00, B0, z_); d0_ = MFMA16(a01, B1, d0_);           \
    f32x4 d1_ = MFMA16(a10, B0, z_); d1_ = MFMA16(a11, B1, d1_);           \
    float csl_ = (CS) * SCALE_HH;                                          \
    _Pragma("unroll")                                                      \
    for (int v = 0; v < 8; v++) {                                          \
      float av_ = (v < 4) ? d0_[v] : d1_[v-4];                             \
      float dd_ = fmaf(-2.f, av_, qsl[v] + csl_);                          \
      if (dd_ <= wq[v]) {                                                  \
        int lq_ = (v>>2)*16 + (l>>4)*4 + (v&3);                            \
        int slot_ = atomicAdd(&cnt[wv][lq_], 1);                           \
        qq[wv][lq_][slot_] = (unsigned short)((T)*16 + cn);                \
      }                                                                    \
    } } while (0)

  #define CHUNK64(B, C, T0)                                                \
    TILE64((T0)+0, B[0], B[1], C[0]); TILE64((T0)+1, B[2], B[3], C[1]);    \
    TILE64((T0)+2, B[4], B[5], C[2]); TILE64((T0)+3, B[6], B[7], C[3])

  LOADC64(0, 0, Bp, Cp);
  for (int win = 0; win < C_RANGE/256; win++) {    // 16 windows
    int cw0 = c0 + win*256;
    LOADC64(win, 4, Bq, Cq);
    CHUNK64(Bp, Cp, 0);
    LOADC64(win, 8, Bp, Cp);
    CHUNK64(Bq, Cq, 4);
    LOADC64(win, 12, Bq, Cq);
    CHUNK64(Bp, Cp, 8);
    if (win < C_RANGE/256 - 1) LOADC64(win+1, 0, Bp, Cp);  // pre-fence prefetch
    CHUNK64(Bq, Cq, 12);

    WAVE_LDS_FENCE();
    int myc = (l < 32) ? cnt[wv][l] : 0;
    if (__any(myc != 0)) {
      if (myc) {
        const float4* qr = (const float4*)(h1 + (size_t)(qw0 + l)*64);
        for (int s = 0; s < myc; s++) {
          int j = cw0 + (int)qq[wv][l][s];
          const float4* cr = (const float4*)(h1 + (size_t)j*64);
          float a = 0.f;
          #pragma unroll 4
          for (int t = 0; t < 16; t++) {
            float4 q = qr[t], c = cr[t];
            a = fmaf(q.x, c.x, a); a = fmaf(q.y, c.y, a);
            a = fmaf(q.z, c.z, a); a = fmaf(q.w, c.w, a);
          }
          float e = (sqi + sqh[j]) - 2.0f*a;
          if (e < maxd || (e == maxd && j < maxi))
            t20_replace_rescan(rd, ri, maxd, maxi, maxp, e, j);
        }
        cnt[wv][l] = 0;
        w19[wv][l] = fminf(maxd, wsv);
      }
      WAVE_LDS_FENCE();
      #pragma unroll
      for (int v = 0; v < 8; v++) wq[v] = w19[wv][(v>>2)*16 + (l>>4)*4 + (v&3)];
    }
  }
  #undef LOADC64
  #undef TILE64
  #undef CHUNK64

  if (l < 32) {
    size_t o = ((size_t)(qw0 + l)*NRANGE + rg)*KNN;
    for (int k = 0; k < KNN; k++) {
      float md = rd[0]; int mi = ri[0]; int mp = 0;
      #pragma unroll
      for (int t = 1; t < KNN; t++) {
        bool g = (rd[t] < md) || (rd[t] == md && ri[t] < mi);
        md = g ? rd[t] : md; mi = g ? ri[t] : mi; mp = g ? t : mp;
      }
      pd[o+k] = md; pi[o+k] = mi;
      #pragma unroll
      for (int t = 0; t < KNN; t++) if (t == mp) rd[t] = INFINITY;
    }
  }
}

// ---------------- knn D=3: subsampled-hist seed + 256-cand-window pipelined scan ----------------
// R15-proven verbatim. Phase 1: bins INFLATED packed-MFMA distances of a 1024-cand
// subsample (windows 0,4,8,12) into per-query 64-bin log histograms (aliased on the queue
// LDS). cumsum>=20 => valid w0 upper bound of the range-20th. Phase 2: 256-cand windows;
// ushort queue; exact rescore drains.
__global__ __launch_bounds__(128, 2) void knn3_wq(const float4* __restrict__ xp,
                                                  const unsigned short* __restrict__ xpa,
                                                  const unsigned short* __restrict__ xpb,
                                                  float* __restrict__ pd,
                                                  int* __restrict__ pi) {
  __shared__ unsigned short qq[2][32][QSW];
  __shared__ float w19[2][32];
  __shared__ int   cnt[2][32];

  int tid = threadIdx.x;
  int wv = tid >> 6;
  int l  = tid & 63;
  int qb = blockIdx.x >> 2, rg = blockIdx.x & 3;
  int q0 = qb*64, c0 = rg*C_RANGE;
  int qw0 = q0 + wv*32;

  float rd[KNN]; int ri[KNN];
  #pragma unroll
  for (int k = 0; k < KNN; k++) { rd[k] = INFINITY; ri[k] = 0x7fffffff; }
  float maxd = INFINITY; int maxi = 0x7fffffff; int maxp = 0;

  float4 qv4 = make_float4(0.f, 0.f, 0.f, 0.f);
  if (l < 32) {
    cnt[wv][l] = 0;
    qv4 = xp[qw0 + l];
  }

  int cn   = l & 15;
  int koff = (l >> 4) * 8;

  bf16x8 aq0 = *(const bf16x8*)(xpa + (size_t)(qw0 + cn)*32 + koff);
  bf16x8 aq1 = *(const bf16x8*)(xpa + (size_t)(qw0 + 16 + cn)*32 + koff);

  float qsr[8], qsp[8];
  #pragma unroll
  for (int v = 0; v < 8; v++) {
    qsr[v] = xp[qw0 + (v>>2)*16 + (l>>4)*4 + (v&3)].w;
    qsp[v] = qsr[v] * SCALE3;
  }

  // ---- phase 1: subsampled histogram prologue (windows 0,4,8,12 = 1024 cands) ----
  unsigned int* hw = (unsigned int*)&qq[wv][0][0];   // [32][HQS] uints, per wave
  for (int t = l; t < 32*HQS; t += 64) hw[t] = 0u;
  WAVE_LDS_FENCE();

  for (int win = 0; win < 16; win += 4) {
    int cw0 = c0 + win*256;
    #pragma unroll
    for (int t = 0; t < 16; t++) {
      int ct = cw0 + t*16;
      bf16x8 bb = *(const bf16x8*)(xpb + (size_t)(ct + cn)*32 + koff);
      f32x4 z = {0.f, 0.f, 0.f, 0.f};
      f32x4 d0 = MFMA16(aq0, bb, z);
      f32x4 d1 = MFMA16(aq1, bb, z);
      float csr = xp[ct + cn].w;
      #pragma unroll
      for (int v = 0; v < 8; v++) {
        float av = (v < 4) ? d0[v] : d1[v-4];
        float uu = fmaf(-2.f, av, (qsr[v] + csr) * 1.0002f);  // >= exact distance
        int lq = (v>>2)*16 + (l>>4)*4 + (v&3);
        atomicAdd(&hw[lq*HQS + hbin(uu)], 1u);
      }
    }
  }
  WAVE_LDS_FENCE();

  float wsv = INFINITY;
  if (l < 32) {
    unsigned int c = 0; int bsel = 64;
    for (int b = 0; b < 64; b++) {
      c += hw[l*HQS + b];
      if (bsel == 64 && c >= 20u) bsel = b;
    }
    if (bsel < 63)
      wsv = __uint_as_float((unsigned int)(bsel + HBIN_BASE + 1) << HBIN_SHIFT);
  }
  WAVE_LDS_FENCE();          // all lanes done reading hw before queue reuse
  if (l < 32) {
    w19[wv][l] = wsv;
    cnt[wv][l] = 0;
  }
  WAVE_LDS_FENCE();
  float wq[8];
  #pragma unroll
  for (int v = 0; v < 8; v++) wq[v] = w19[wv][(v>>2)*16 + (l>>4)*4 + (v&3)];

  // ---- phase 2: pipelined main scan (256-cand windows, 4 rolling 4-tile chunks) ----
  bf16x8 Bp[4], Bq[4]; float Cp[4], Cq[4];

  #define LOADC3(WIN, T0, B, C) do { int cw_ = c0 + (WIN)*256;             \
    _Pragma("unroll")                                                      \
    for (int t_ = 0; t_ < 4; t_++) {                                       \
      int ct_ = cw_ + ((T0)+t_)*16;                                        \
      B[t_] = *(const bf16x8*)(xpb + (size_t)(ct_ + cn)*32 + koff);        \
      C[t_] = xp[ct_ + cn].w;                                              \
    } } while (0)

  #define TILE3(T, BB, CS) do {                                            \
    f32x4 z_ = {0.f, 0.f, 0.f, 0.f};                                       \
    f32x4 d0_ = MFMA16(aq0, BB, z_);                                       \
    f32x4 d1_ = MFMA16(aq1, BB, z_);                                       \
    float csp_ = (CS) * SCALE3;                                            \
    _Pragma("unroll")                                                      \
    for (int v = 0; v < 8; v++) {                                          \
      float av_ = (v < 4) ? d0_[v] : d1_[v-4];                             \
      float dd_ = fmaf(-2.f, av_, qsp[v] + csp_);                          \
      if (dd_ <= wq[v]) {                                                  \
        int lq_ = (v>>2)*16 + (l>>4)*4 + (v&3);                            \
        int slot_ = atomicAdd(&cnt[wv][lq_], 1);                           \
        qq[wv][lq_][slot_] = (unsigned short)((T)*16 + cn);                \
      }                                                                    \
    } } while (0)

  #define CHUNK3(B, C, T0)                                                 \
    TILE3((T0)+0, B[0], C[0]); TILE3((T0)+1, B[1], C[1]);                  \
    TILE3((T0)+2, B[2], C[2]); TILE3((T0)+3, B[3], C[3])

  LOADC3(0, 0, Bp, Cp);
  for (int win = 0; win < 16; win++) {
    int cw0 = c0 + win*256;
    LOADC3(win, 4, Bq, Cq);
    CHUNK3(Bp, Cp, 0);
    LOADC3(win, 8, Bp, Cp);
    CHUNK3(Bq, Cq, 4);
    LOADC3(win, 12, Bq, Cq);
    CHUNK3(Bp, Cp, 8);
    if (win < 15) LOADC3(win+1, 0, Bp, Cp);   // pre-fence prefetch
    CHUNK3(Bq, Cq, 12);

    WAVE_LDS_FENCE();
    int myc = (l < 32) ? cnt[wv][l] : 0;
    if (__any(myc != 0)) {
      if (myc) {
        for (int s = 0; s < myc; s++) {
          int j = cw0 + (int)qq[wv][l][s];
          float4 cv4 = xp[j];
          float e = (qv4.w + cv4.w)
                  - 2.0f*(qv4.x*cv4.x + qv4.y*cv4.y + qv4.z*cv4.z);
          if (e < maxd || (e == maxd && j < maxi))
            t20_replace_rescan(rd, ri, maxd, maxi, maxp, e, j);
        }
        cnt[wv][l] = 0;
        w19[wv][l] = fminf(maxd, wsv);
      }
      WAVE_LDS_FENCE();
      #pragma unroll
      for (int v = 0; v < 8; v++) wq[v] = w19[wv][(v>>2)*16 + (l>>4)*4 + (v&3)];
    }
  }
  #undef LOADC3
  #undef TILE3
  #undef CHUNK3

  if (l < 32) {
    size_t o = ((size_t)(qw0 + l)*NRANGE + rg)*KNN;
    for (int k = 0; k < KNN; k++) {
      float md = rd[0]; int mi = ri[0]; int mp = 0;
      #pragma unroll
      for (int t = 1; t < KNN; t++) {
        bool g = (rd[t] < md) || (rd[t] == md && ri[t] < mi);
        md = g ? rd[t] : md; mi = g ? ri[t] : mi; mp = g ? t : mp;
      }
      pd[o+k] = md; pi[o+k] = mi;
      #pragma unroll
      for (int t = 0; t < KNN; t++) if (t == mp) rd[t] = INFINITY;
    }
  }
}

// ---------------- merge NRANGE sorted partial lists -> top-20 (256 blocks: 1/CU) ----------
__global__ void knn_merge_kernel(const float* __restrict__ pd, const int* __restrict__ pi,
                                 int* __restrict__ out_idx) {
  int qi = blockIdx.x*64 + threadIdx.x;
  const float* bd = pd + (size_t)qi*NRANGE*KNN;
  const int*   bi = pi + (size_t)qi*NRANGE*KNN;
  int ptr[NRANGE];
  #pragma unroll
  for (int r=0;r<NRANGE;r++) ptr[r] = 0;
  for (int k = 0; k < KNN; k++) {
    float best = INFINITY; int besti = 0x7fffffff; int br = 0;
    #pragma unroll
    for (int r = 0; r < NRANGE; r++) {
      float d = bd[r*KNN + ptr[r]];
      int   ii = bi[r*KNN + ptr[r]];
      bool better = (ptr[r] < KNN) && (d < best || (d == best && ii < besti));
      if (better) { best = d; besti = ii; br = r; }
    }
    #pragma unroll
    for (int r=0;r<NRANGE;r++) ptr[r] += (r == br) ? 1 : 0;
    out_idx[qi*KNN + k] = besti;
  }
}

// ---------------- fused edge_conv1 + gather+max+relu + bf16-hi emit, LDS-staged ----------
// R19-proven math; NEW: the block's 16 points x 20 neighbor coords are staged in LDS
// cooperatively (320 gathers instead of 16x5120 redundant per-channel-group gathers).
// Coords pass through LDS bit-exactly; per-channel expressions and j-ascending fmax
// chain unchanged -> bit-identical h1/bh.
__global__ __launch_bounds__(256) void mrt64_kernel(const float* __restrict__ x,
                                                    const float* __restrict__ W1,
                                                    const float* __restrict__ b1,
                                                    const int* __restrict__ idx,
                                                    float* __restrict__ out,
                                                    unsigned short* __restrict__ bh) {
  __shared__ float nb[16][KNN][3];   // neighbor coords
  __shared__ float px[16][3];        // own coords
  int tid = threadIdx.x;
  int i0 = blockIdx.x * 16;          // 1024 blocks x 16 points
  for (int t = tid; t < 16*KNN; t += 256) {
    int p = t / KNN, j = t % KNN;
    int jj = idx[(i0 + p)*KNN + j];
    nb[p][j][0] = x[jj*3+0];
    nb[p][j][1] = x[jj*3+1];
    nb[p][j][2] = x[jj*3+2];
  }
  if (tid < 48) px[tid/3][tid%3] = x[(i0 + tid/3)*3 + tid%3];
  __syncthreads();

  int pt = tid >> 4, c4 = tid & 15;
  int i = i0 + pt;
  float wt0[4], wt1[4], wt2[4], wb0[4], wb1[4], wb2[4], bb[4];
  #pragma unroll
  for (int k = 0; k < 4; k++) {
    int c = c4*4 + k;
    wt0[k] = W1[0*64+c]; wt1[k] = W1[1*64+c]; wt2[k] = W1[2*64+c];
    wb0[k] = W1[3*64+c]; wb1[k] = W1[4*64+c]; wb2[k] = W1[5*64+c];
    bb[k]  = b1[c];
  }
  float x0 = px[pt][0], x1 = px[pt][1], x2 = px[pt][2];
  float base[4], m[4];
  #pragma unroll
  for (int k = 0; k < 4; k++) {
    base[k] = x0*(wt0[k]-wb0[k]) + x1*(wt1[k]-wb1[k]) + x2*(wt2[k]-wb2[k]) + bb[k];
    m[k] = -INFINITY;
  }
  for (int j = 0; j < KNN; j++) {
    float y0 = nb[pt][j][0], y1 = nb[pt][j][1], y2 = nb[pt][j][2];
    #pragma unroll
    for (int k = 0; k < 4; k++) {
      float g = y0*wb0[k] + y1*wb1[k] + y2*wb2[k];
      m[k] = fmaxf(m[k], base[k] + g);
    }
  }
  float4 o;
  o.x = fmaxf(m[0], 0.0f); o.y = fmaxf(m[1], 0.0f);
  o.z = fmaxf(m[2], 0.0f); o.w = fmaxf(m[3], 0.0f);
  *(float4*)(out + (size_t)i*64 + c4*4) = o;
  ushort4 hv;
  hv.x = f2bf(o.x); hv.y = f2bf(o.y); hv.z = f2bf(o.z); hv.w = f2bf(o.w);
  ((ushort4*)bh)[i*16 + c4] = hv;
}

// ---------------- edge_conv2, 8 points/block (weight reuse x8; wd2 fused inline) ---------
__global__ __launch_bounds__(128) void cg2_kernel(const float* __restrict__ h1,
                                                  const float* __restrict__ W2,
                                                  const float* __restrict__ b2,
                                                  float* __restrict__ C2,
                                                  float* __restrict__ G2) {
  __shared__ float h1s[8][64];
  int i0 = blockIdx.x*8, c = threadIdx.x;   // 2048 blocks x 128
  for (int t = c; t < 512; t += 128)
    h1s[t>>6][t&63] = h1[(size_t)(i0 + (t>>6))*64 + (t&63)];
  __syncthreads();
  float a[8] = {0.f,0.f,0.f,0.f,0.f,0.f,0.f,0.f};
  float g[8] = {0.f,0.f,0.f,0.f,0.f,0.f,0.f,0.f};
  for (int d = 0; d < 64; d++) {
    float wt = W2[d*128 + c];
    float wb = W2[(d+64)*128 + c];
    float wd = wt - wb;
    #pragma unroll
    for (int p = 0; p < 8; p++) {
      float hv = h1s[p][d];
      a[p] += hv * wd;
      g[p] += hv * wb;
    }
  }
  float bv = b2[c];
  #pragma unroll
  for (int p = 0; p < 8; p++) {
    C2[(size_t)(i0+p)*128 + c] = a[p] + bv;
    G2[(size_t)(i0+p)*128 + c] = g[p];
  }
}

// ---------------- fused maxrelu(C=128)+fc1+fc2, 8 points/block (weight reuse x8) ---------
__global__ __launch_bounds__(128) void mrfc_kernel(const float* __restrict__ C2,
                                                   const float* __restrict__ G2,
                                                   const int* __restrict__ idx,
                                                   const float* __restrict__ w1,
                                                   const float* __restrict__ b1,
                                                   const float* __restrict__ w2,
                                                   const float* __restrict__ b2,
                                                   float* __restrict__ out) {
  __shared__ float h2r[8][128];
  __shared__ float f1r[8][128];
  int i0 = blockIdx.x*8, c = threadIdx.x;   // 2048 blocks x 128
  #pragma unroll
  for (int p = 0; p < 8; p++) {
    int i = i0 + p;
    float base = C2[(size_t)i*128 + c];
    float m = -INFINITY;
    for (int j = 0; j < KNN; j++) {
      int jj = idx[i*KNN + j];
      m = fmaxf(m, base + G2[(size_t)jj*128 + c]);
    }
    h2r[p][c] = fmaxf(m, 0.0f);
  }
  __syncthreads();
  float a[8] = {0.f,0.f,0.f,0.f,0.f,0.f,0.f,0.f};
  for (int d = 0; d < 128; d++) {
    float wv = w1[d*128 + c];
    #pragma unroll
    for (int p = 0; p < 8; p++) a[p] += h2r[p][d] * wv;
  }
  float b1v = b1[c];
  #pragma unroll
  for (int p = 0; p < 8; p++) f1r[p][c] = fmaxf(a[p] + b1v, 0.0f);
  __syncthreads();
  if (c < 40) {
    float a2[8] = {0.f,0.f,0.f,0.f,0.f,0.f,0.f,0.f};
    for (int d = 0; d < 128; d++) {
      float wv = w2[d*40 + c];
      #pragma unroll
      for (int p = 0; p < 8; p++) a2[p] += f1r[p][d] * wv;
    }
    float b2v = b2[c];
    #pragma unroll
    for (int p = 0; p < 8; p++) out[(i0+p)*40 + c] = a2[p] + b2v;
  }
}

extern "C" void kernel_launch(void* const* d_in, const int* in_sizes, int n_in,
                              void* d_out, int out_size, void* d_ws, size_t ws_size,
                              hipStream_t stream) {
  (void)in_sizes; (void)n_in; (void)out_size; (void)ws_size;
  const float* x     = (const float*)d_in[0];
  const float* W1    = (const float*)d_in[1];
  const float* b1    = (const float*)d_in[2];
  const float* W2    = (const float*)d_in[3];
  const float* b2    = (const float*)d_in[4];
  const float* fc1_w = (const float*)d_in[5];
  const float* fc1_b = (const float*)d_in[6];
  const float* fc2_w = (const float*)d_in[7];
  const float* fc2_b = (const float*)d_in[8];
  float* out = (float*)d_out;

  // ---- workspace (31.03 MB, lifetime-disjoint aliasing; R19 layout) ----
  char* ws = (char*)d_ws;
  float4* xp4 = (float4*)(ws + 0);          // 262144
  float*  sqh = (float*) (ws + 262144);     // 65536
  int*    idx = (int*)   (ws + 327680);     // 1310720
  float*  h1  = (float*) (ws + 1671168);    // 4194304 -> 5865472
  unsigned short* xpa = (unsigned short*)(ws + 1671168); // 1MB, dead before h1 written
  unsigned short* xpb = (unsigned short*)(ws + 2719744); // 1MB, dead before h1 written
  unsigned short* hbh = (unsigned short*)(ws + 5865472); // 2097152 -> 7962624
  float*  wsd = (float*) (ws + 10059776);   // 65536
  float*  A   = (float*) (ws + 14254080);   // 8388608 -> 22642688
  float*  C2  = A;
  float*  G2  = (float*) (ws + 22642688);   // 8388608 -> 31031296
  int*    pi  = (int*)   (ws + 14254080);   // 5.25MB (aliases A; A dead during knn phases)
  float*  pd  = (float*) (ws + 22642688);   // 5.25MB (aliases G2; G2 dead during knn phases)

  pack_kernel  <<<256,    64, 0, stream>>>(x, xp4, xpa, xpb);
  knn3_wq      <<<1024,  128, 0, stream>>>(xp4, xpa, xpb, pd, pi);
  knn_merge_kernel<<<256, 64, 0, stream>>>(pd, pi, idx);
  mrt64_kernel <<<1024,  256, 0, stream>>>(x, W1, b1, idx, h1, hbh);
  sq64_kernel  <<<256,    64, 0, stream>>>(h1, sqh);
  seed64_kernel<<<256,   256, 0, stream>>>(h1, sqh, idx, wsd);
  knn64_wq     <<<1024,  128, 0, stream>>>(h1, hbh, sqh, wsd, pd, pi);
  knn_merge_kernel<<<256, 64, 0, stream>>>(pd, pi, idx);
  cg2_kernel   <<<2048,  128, 0, stream>>>(h1, W2, b2, C2, G2);
  mrfc_kernel  <<<2048,  128, 0, stream>>>(C2, G2, idx, fc1_w, fc1_b, fc2_w, fc2_b, out);
}